// Round 2
// baseline (325.242 us; speedup 1.0000x reference)
//
#include <hip/hip_runtime.h>
#include <math.h>

#define LNB      32
#define NODE_IN  128
#define EDGE_IN  64
#define TIME_D   128
#define D_MODEL  320
#define N_HEAD   8
#define D_K      64
#define NHD      512
#define HID      128
#define IN2      448
#define N_DSTN   8192

typedef __attribute__((ext_vector_type(8))) short bf16x8;
typedef __attribute__((ext_vector_type(4))) float f32x4;
#define MFMA16(a,b,c) __builtin_amdgcn_mfma_f32_16x16x32_bf16(a,b,c,0,0,0)

// ---- ws layout (elements of unsigned short) ----
#define WS_QKM   0            // 8192*2560 : qk (h-major) -> mbar (d*8+h layout), in place
#define WS_WQK   20971520     // 2560*128  : folded wk@wq   (row-major [h*320+d][k])
#define WS_WVF   21299200     // 320*2560  : folded fcw@wv  ([c][d*8+h])
#define WS_NWC   22118400     // 128*448   : [nw1 | nw2*lng]
#define WS_F32   22175744     // 3520 floats
#define WS_X     22182784     // 8192*320 f32 accumulation buffer
// total = 27,425,664 shorts = 54.9 MB

#define F_C0     0            // 512
#define F_C0K    512          // 2560
#define F_CC     3072         // 320 : fcb + q-const residual
#define F_B2     3392         // 128 : nb + nw2@lnb

// native RTNE f32->bf16 (v_cvt_pk_bf16_f32 on gfx950) — bit-identical to manual RTNE
__device__ __forceinline__ unsigned short f2bf(float f) {
  __bf16 h = (__bf16)f;
  return __builtin_bit_cast(unsigned short, h);
}
__device__ __forceinline__ bf16x8 pack8(const float* v) {
  unsigned short b8[8];
  #pragma unroll
  for (int j = 0; j < 8; ++j) b8[j] = f2bf(v[j]);
  return *(const bf16x8*)b8;
}

// =================== prep1a: elementwise folds ==============================
__global__ __launch_bounds__(256)
void prep1a(const float* __restrict__ nw, const float* __restrict__ lng,
            const float* __restrict__ fcb, const float* __restrict__ ph,
            unsigned short* __restrict__ ws)
{
  int i = blockIdx.x * 256 + threadIdx.x;
  unsigned short* nwc = ws + WS_NWC;
  float* f32r = (float*)(ws + WS_F32);
  if (i < 16384) {                       // nw1 cast
    int o = i >> 7, k = i & 127;
    nwc[o * IN2 + k] = f2bf(nw[(size_t)o * IN2 + k]);
  } else if (i < 57344) {                // nw2g = nw2 * lng
    int j = i - 16384, o = j / 320, c = j - o * 320;
    nwc[o * IN2 + 128 + c] = f2bf(nw[(size_t)o * IN2 + 128 + c] * lng[c]);
  } else if (i < 57664) {                // cc[c] = fcb + q-const
    int c = i - 57344;
    f32r[F_CC + c] = fcb[c] + (c >= 192 ? __cosf(ph[c - 192]) : 0.f);
  }
}

// =================== prep1b: c0 (512 waves) + b2 (128 waves) ===============
__global__ __launch_bounds__(256)
void prep1b(const float* __restrict__ wq, const float* __restrict__ ph,
            const float* __restrict__ nw, const float* __restrict__ lnb_,
            const float* __restrict__ nb, unsigned short* __restrict__ ws)
{
  float* f32r = (float*)(ws + WS_F32);
  int gw = (blockIdx.x * 256 + threadIdx.x) >> 6;
  int ln = threadIdx.x & 63;
  if (gw < 512) {                        // c0[j] = cos(ph) . wq[j][192:]
    float s = __cosf(ph[ln])      * wq[(size_t)gw * D_MODEL + 192 + ln]
            + __cosf(ph[ln + 64]) * wq[(size_t)gw * D_MODEL + 256 + ln];
    #pragma unroll
    for (int off = 32; off >= 1; off >>= 1) s += __shfl_xor(s, off);
    if (ln == 0) f32r[F_C0 + gw] = s;
  } else {                               // b2[o] = nb + nw2 . lnb
    int o = gw - 512;
    float s = 0.f;
    #pragma unroll
    for (int k = 0; k < 5; ++k) {
      int c = ln + 64 * k;
      s += nw[(size_t)o * IN2 + 128 + c] * lnb_[c];
    }
    #pragma unroll
    for (int off = 32; off >= 1; off >>= 1) s += __shfl_xor(s, off);
    if (ln == 0) f32r[F_B2 + o] = nb[o] + s;
  }
}

// =================== prep_c0k: one wave per hd ==============================
__global__ __launch_bounds__(256)
void prep_c0k(const float* __restrict__ wk, unsigned short* __restrict__ ws)
{
  float* f32r = (float*)(ws + WS_F32);
  int gw = (blockIdx.x * 256 + threadIdx.x) >> 6;   // 0..2559
  int ln = threadIdx.x & 63;
  int h = gw / 320, d = gw - h * 320;
  float s = f32r[F_C0 + h * 64 + ln] * wk[(size_t)(h * 64 + ln) * D_MODEL + d];
  #pragma unroll
  for (int off = 32; off >= 1; off >>= 1) s += __shfl_xor(s, off);
  if (ln == 0) f32r[F_C0K + gw] = s;
}

// =================== prep_wqk: LDS-tiled fold (80 blocks) ===================
__global__ __launch_bounds__(256)
void prep_wqk(const float* __restrict__ wq, const float* __restrict__ wk,
              unsigned short* __restrict__ ws)
{
  __shared__ float sQw[64 * 128];
  __shared__ float sKw[64 * 32];
  int h = blockIdx.x / 10, d0 = (blockIdx.x - h * 10) * 32;
  int tid = threadIdx.x;
  #pragma unroll 4
  for (int it = 0; it < 32; ++it) {
    int idx = it * 256 + tid;
    int r = idx >> 7, c = idx & 127;
    sQw[idx] = wq[(size_t)(h * 64 + r) * D_MODEL + c];
  }
  #pragma unroll
  for (int it = 0; it < 8; ++it) {
    int idx = it * 256 + tid;
    int r = idx >> 5, c = idx & 31;
    sKw[idx] = wk[(size_t)(h * 64 + r) * D_MODEL + d0 + c];
  }
  __syncthreads();
  int di = tid >> 3, k0 = (tid & 7) * 16;
  float acc[16] = {};
  for (int dk = 0; dk < 64; ++dk) {
    float w = sKw[dk * 32 + di];
    #pragma unroll
    for (int j = 0; j < 16; ++j) acc[j] += w * sQw[dk * 128 + k0 + j];
  }
  unsigned short* dst = ws + WS_WQK + (size_t)(h * 320 + d0 + di) * 128 + k0;
  #pragma unroll
  for (int j = 0; j < 16; ++j) dst[j] = f2bf(acc[j]);
}

// =================== prep_wvf: LDS-tiled fold (800 blocks) ==================
// wvf[c][d*8+h] = sum_jj fcw[c][h*64+jj] * wv[h*64+jj][d]
__global__ __launch_bounds__(256)
void prep_wvf(const float* __restrict__ fcw, const float* __restrict__ wv,
              unsigned short* __restrict__ ws)
{
  __shared__ float sF[32 * 64];
  __shared__ float sW[64 * 32];
  int b = blockIdx.x;
  int h = b / 100, r2 = b - h * 100;
  int ct = r2 / 10;
  int c0 = ct * 32, d0 = (r2 - ct * 10) * 32;
  int tid = threadIdx.x;
  #pragma unroll
  for (int it = 0; it < 8; ++it) {
    int idx = it * 256 + tid;
    int i = idx >> 6, jj = idx & 63;
    sF[idx] = fcw[(size_t)(c0 + i) * NHD + h * 64 + jj];
  }
  #pragma unroll
  for (int it = 0; it < 8; ++it) {
    int idx = it * 256 + tid;
    int jj = idx >> 5, i = idx & 31;
    sW[idx] = wv[(size_t)(h * 64 + jj) * D_MODEL + d0 + i];
  }
  __syncthreads();
  int ci = tid >> 3, dj0 = (tid & 7) * 4;
  float acc[4] = {};
  for (int jj = 0; jj < 64; ++jj) {
    float f = sF[ci * 64 + jj];
    #pragma unroll
    for (int k = 0; k < 4; ++k) acc[k] += f * sW[jj * 32 + dj0 + k];
  }
  unsigned short* wvf = ws + WS_WVF;
  #pragma unroll
  for (int k = 0; k < 4; ++k)
    wvf[(size_t)(c0 + ci) * 2560 + (size_t)(d0 + dj0 + k) * 8 + h] = f2bf(acc[k]);
}

// =================== K1: qk = nf @ wqk^T + c0k  (h-major layout) ============
__global__ __launch_bounds__(256, 6)
void tgat_qk(const float* __restrict__ nf, const unsigned short* __restrict__ ws,
             unsigned short* __restrict__ qkm)
{
  __shared__ alignas(16) unsigned short sA[64 * 136];
  const int tid = threadIdx.x, wid = tid >> 6, lane = tid & 63, qd = lane >> 4, lm = lane & 15;
  const int mt_blk = blockIdx.x / 20, nt_blk = blockIdx.x - mt_blk * 20;
  const int n0 = mt_blk * 64, c0 = nt_blk * 128;
  const unsigned short* wqk = ws + WS_WQK;
  const float* f32r = (const float*)(ws + WS_F32);

  { // stage A: 64 x 128 bf16 (coalesced)
    int n = tid >> 2, k0 = (tid & 3) * 32;
    const float4* src = (const float4*)(nf + (size_t)(n0 + n) * NODE_IN + k0);
    #pragma unroll
    for (int q = 0; q < 4; ++q) {
      float4 f0 = src[2 * q], f1 = src[2 * q + 1];
      float v[8] = {f0.x, f0.y, f0.z, f0.w, f1.x, f1.y, f1.z, f1.w};
      *(bf16x8*)&sA[n * 136 + k0 + q * 8] = pack8(v);
    }
  }
  __syncthreads();

  f32x4 acc[2][4] = {};
  for (int kt = 0; kt < 4; ++kt) {
    bf16x8 a[4];
    #pragma unroll
    for (int mt = 0; mt < 4; ++mt)
      a[mt] = *(const bf16x8*)&sA[(mt * 16 + lm) * 136 + kt * 32 + qd * 8];
    #pragma unroll
    for (int t = 0; t < 2; ++t) {
      int cg = c0 + (2 * wid + t) * 16 + lm;
      bf16x8 b = *(const bf16x8*)&wqk[(size_t)cg * 128 + kt * 32 + qd * 8];
      #pragma unroll
      for (int mt = 0; mt < 4; ++mt) acc[t][mt] = MFMA16(a[mt], b, acc[t][mt]);
    }
  }
  #pragma unroll
  for (int t = 0; t < 2; ++t) {
    int cg = c0 + (2 * wid + t) * 16 + lm;
    float ck = f32r[F_C0K + cg];
    #pragma unroll
    for (int mt = 0; mt < 4; ++mt)
      #pragma unroll
      for (int r = 0; r < 4; ++r)
        qkm[(size_t)(n0 + mt * 16 + qd * 4 + r) * 2560 + cg] = f2bf(acc[t][mt][r] + ck);
  }
}

// =================== K2: attention (one barrier before scores) ==============
__global__ __launch_bounds__(256, 6)
void tgat_attn(const float* __restrict__ nf, const float* __restrict__ ef,
               const float* __restrict__ dtp, const int* __restrict__ nidx,
               const float* __restrict__ freq, const float* __restrict__ ph,
               unsigned short* __restrict__ qkm)
{
  __shared__ alignas(16) unsigned short sM[LNB * 328];    // 21 KB
  __shared__ alignas(16) unsigned short sATT[16 * 40];    // 1.25 KB

  const int tid = threadIdx.x;
  const int wid = tid >> 6, lane = tid & 63, qd = lane >> 4, lm = lane & 15;
  const int n = blockIdx.x;
  unsigned short* qn = qkm + (size_t)n * 2560;

  // ---- m build: thread -> (l = g&31, 8 consecutive d); tables direct from L2
  #pragma unroll 1
  for (int it = 0; it < 5; ++it) {
    int g = it * 256 + tid;
    int l = g & 31, dg = g >> 5;
    int d0 = dg * 8;
    float v[8];
    if (dg < 16) {
      int ni = nidx[n * 16 + (l >> 1)];
      const float4* src = (const float4*)(nf + (size_t)ni * NODE_IN + d0);
      float4 f0 = src[0], f1 = src[1];
      v[0]=f0.x; v[1]=f0.y; v[2]=f0.z; v[3]=f0.w; v[4]=f1.x; v[5]=f1.y; v[6]=f1.z; v[7]=f1.w;
    } else if (dg < 24) {
      const float4* src = (const float4*)(ef + ((size_t)n * LNB + l) * EDGE_IN + (d0 - NODE_IN));
      float4 f0 = src[0], f1 = src[1];
      v[0]=f0.x; v[1]=f0.y; v[2]=f0.z; v[3]=f0.w; v[4]=f1.x; v[5]=f1.y; v[6]=f1.z; v[7]=f1.w;
    } else {
      int dd = d0 - 192;
      float dt = dtp[(size_t)n * LNB + l];
      const float4* fq = (const float4*)(freq + dd);
      const float4* pp = (const float4*)(ph + dd);
      float4 q0 = fq[0], q1 = fq[1], p0 = pp[0], p1 = pp[1];
      v[0] = __cosf(dt * q0.x + p0.x); v[1] = __cosf(dt * q0.y + p0.y);
      v[2] = __cosf(dt * q0.z + p0.z); v[3] = __cosf(dt * q0.w + p0.w);
      v[4] = __cosf(dt * q1.x + p1.x); v[5] = __cosf(dt * q1.y + p1.y);
      v[6] = __cosf(dt * q1.z + p1.z); v[7] = __cosf(dt * q1.w + p1.w);
    }
    *(bf16x8*)&sM[l * 328 + d0] = pack8(v);
  }

  // wave0: issue qk B-frag loads now — latency hides under the barrier wait
  bf16x8 qfrag[10];
  if (wid == 0) {
    #pragma unroll
    for (int kt = 0; kt < 10; ++kt) {
      qfrag[kt] = (bf16x8){0,0,0,0,0,0,0,0};
      if (lm < 8) qfrag[kt] = *(const bf16x8*)&qn[lm * 320 + kt * 32 + qd * 8];
    }
  }
  __syncthreads();                       // barrier 1: m ready

  // mbar tile ownership: wave0 -> 2 tiles, waves1-3 -> 6 each (20 total)
  const int tbeg = (wid == 0) ? 0 : 2 + (wid - 1) * 6;
  const int tcnt = (wid == 0) ? 2 : 6;
  bf16x8 afr[6];

  if (wid == 0) {
    // scores: D[l][h] = m @ qk^T / 8
    f32x4 acc0 = {}, acc1 = {};
    #pragma unroll
    for (int kt = 0; kt < 10; ++kt) {
      bf16x8 a0 = *(const bf16x8*)&sM[lm * 328 + kt * 32 + qd * 8];
      bf16x8 a1 = *(const bf16x8*)&sM[(16 + lm) * 328 + kt * 32 + qd * 8];
      acc0 = MFMA16(a0, qfrag[kt], acc0);
      acc1 = MFMA16(a1, qfrag[kt], acc1);
    }
    float s[8], e[8];
    #pragma unroll
    for (int r = 0; r < 4; ++r) { s[r] = acc0[r] * 0.125f; s[4 + r] = acc1[r] * 0.125f; }
    float mx = s[0];
    #pragma unroll
    for (int i = 1; i < 8; ++i) mx = fmaxf(mx, s[i]);
    mx = fmaxf(mx, __shfl_xor(mx, 16));
    mx = fmaxf(mx, __shfl_xor(mx, 32));
    float sum = 0.f;
    #pragma unroll
    for (int i = 0; i < 8; ++i) { e[i] = __expf(s[i] - mx); sum += e[i]; }
    sum += __shfl_xor(sum, 16);
    sum += __shfl_xor(sum, 32);
    float inv = 1.f / sum;
    #pragma unroll
    for (int i = 0; i < 8; ++i) {
      int l = (i < 4) ? (qd * 4 + i) : (16 + qd * 4 + (i - 4));
      sATT[lm * 40 + l] = f2bf(e[i] * inv);
    }
  } else {
    // waves 1-3: prefetch transposed-m A-frags for my 6 tiles (overlaps softmax)
    #pragma unroll
    for (int u = 0; u < 6; ++u) {
      int d = (tbeg + u) * 16 + lm;
      unsigned short a8[8];
      #pragma unroll
      for (int j = 0; j < 8; ++j) a8[j] = sM[(qd * 8 + j) * 328 + d];
      afr[u] = *(const bf16x8*)a8;
    }
  }
  __syncthreads();                       // barrier 2: sATT ready

  if (wid == 0) {                        // wave0 fetches its 2 tiles now
    #pragma unroll
    for (int u = 0; u < 2; ++u) {
      int d = u * 16 + lm;
      unsigned short a8[8];
      #pragma unroll
      for (int j = 0; j < 8; ++j) a8[j] = sM[(qd * 8 + j) * 328 + d];
      afr[u] = *(const bf16x8*)a8;
    }
  }
  bf16x8 batt = *(const bf16x8*)&sATT[lm * 40 + qd * 8];
  #pragma unroll
  for (int u = 0; u < 6; ++u) {
    if (u < tcnt) {                      // wave-uniform guard
      int dtile = tbeg + u;
      f32x4 acc = {};
      acc = MFMA16(afr[u], batt, acc);
      if (lm < 8) {
        #pragma unroll
        for (int r = 0; r < 4; ++r)
          qn[(dtile * 16 + qd * 4 + r) * 8 + lm] = f2bf(acc[r]);
      }
    }
  }
}

// =================== K3a: x = mbar @ wvf^T (full-K, no atomics) =============
// 512 blocks x 512 thr. mb = bid&127 (64 rows), ns = bid>>7 (80-col slice).
// 128 ≡ 0 (mod 8): the 4 ns-blocks of one mb land on the SAME XCD -> A-rows
// fetched from HBM once, re-read from L2. 8 waves = 4 m-tiles x 2 k-halves;
// both k-half chunks staged per iter; one LDS f32 reduce merges halves;
// plain stores (no atomicAdd, no memset).
__global__ __launch_bounds__(512, 4)
void tgat_xgemm(const unsigned short* __restrict__ ws,
                const unsigned short* __restrict__ qkm, float* __restrict__ xacc)
{
  __shared__ alignas(16) unsigned short sA[2][64 * 136];  // 34.8 KB
  __shared__ float sRed[64 * 80];                         // 20 KB
  const int tid = threadIdx.x, wid = tid >> 6, lane = tid & 63;
  const int qd = lane >> 4, lm = lane & 15;
  const int ns = blockIdx.x >> 7, mb = blockIdx.x & 127;
  const int n0 = mb * 64, c0 = ns * 80;
  const int kh = wid >> 2, wm = wid & 3;
  const unsigned short* wvf = ws + WS_WVF;

  const int sb = tid >> 8, tt = tid & 255;   // staging: which k-half buffer
  const int srow = tt >> 2, sp = (tt & 3) * 32;

  f32x4 acc[5] = {};
  for (int it = 0; it < 10; ++it) {
    __syncthreads();
    { // stage both k-half chunks: 64 rows x 128 k each (64 B/thread)
      const unsigned short* src =
          qkm + (size_t)(n0 + srow) * 2560 + sb * 1280 + it * 128 + sp;
      *(bf16x8*)&sA[sb][srow * 136 + sp]      = *(const bf16x8*)(src);
      *(bf16x8*)&sA[sb][srow * 136 + sp + 8]  = *(const bf16x8*)(src + 8);
      *(bf16x8*)&sA[sb][srow * 136 + sp + 16] = *(const bf16x8*)(src + 16);
      *(bf16x8*)&sA[sb][srow * 136 + sp + 24] = *(const bf16x8*)(src + 24);
    }
    __syncthreads();
    #pragma unroll
    for (int kt = 0; kt < 4; ++kt) {
      bf16x8 a = *(const bf16x8*)&sA[kh][(wm * 16 + lm) * 136 + kt * 32 + qd * 8];
      #pragma unroll
      for (int u = 0; u < 5; ++u) {
        int c = c0 + u * 16 + lm;
        bf16x8 b = *(const bf16x8*)
            &wvf[(size_t)c * 2560 + kh * 1280 + it * 128 + kt * 32 + qd * 8];
        acc[u] = MFMA16(a, b, acc[u]);
      }
    }
  }
  __syncthreads();
  if (kh == 1) {
    #pragma unroll
    for (int u = 0; u < 5; ++u)
      #pragma unroll
      for (int r = 0; r < 4; ++r)
        sRed[(wm * 16 + qd * 4 + r) * 80 + u * 16 + lm] = acc[u][r];
  }
  __syncthreads();
  if (kh == 0) {
    #pragma unroll
    for (int u = 0; u < 5; ++u)
      #pragma unroll
      for (int r = 0; r < 4; ++r) {
        float v = acc[u][r] + sRed[(wm * 16 + qd * 4 + r) * 80 + u * 16 + lm];
        xacc[(size_t)(n0 + wm * 16 + qd * 4 + r) * 320 + c0 + u * 16 + lm] = v;
      }
  }
}

// =================== K3b: LN + out GEMM (512 blocks) ========================
__global__ __launch_bounds__(256, 4)
void tgat_post2(const float* __restrict__ nf, const unsigned short* __restrict__ ws,
                const float* __restrict__ xacc, float* __restrict__ out)
{
  __shared__ alignas(16) unsigned short sQb[16 * 136];
  __shared__ alignas(16) unsigned short sXb[16 * 328];
  const int tid = threadIdx.x, wid = tid >> 6, lane = tid & 63, qd = lane >> 4, lm = lane & 15;
  const int n0 = blockIdx.x * 16;
  const unsigned short* nwc = ws + WS_NWC;
  const float* f32r = (const float*)(ws + WS_F32);

  { // stage h_dst bf16
    int nn = tid >> 4, kk = (tid & 15) * 8;
    const float4* src = (const float4*)(nf + (size_t)(n0 + nn) * NODE_IN + kk);
    float4 f0 = src[0], f1 = src[1];
    float v8[8] = {f0.x, f0.y, f0.z, f0.w, f1.x, f1.y, f1.z, f1.w};
    *(bf16x8*)&sQb[nn * 136 + kk] = pack8(v8);
  }
  // LN: thread owns (row rr, cols cl+16u); reduce over the 16-lane row group
  const int rr = tid >> 4, cl = tid & 15;
  float v[20], s1 = 0.f, s2 = 0.f;
  #pragma unroll
  for (int u = 0; u < 20; ++u) {
    int c = u * 16 + cl;
    float x = xacc[(size_t)(n0 + rr) * 320 + c] + f32r[F_CC + c];
    if (c < 128) x += nf[(size_t)(n0 + rr) * NODE_IN + c];
    v[u] = x; s1 += x; s2 += x * x;
  }
  #pragma unroll
  for (int off = 8; off >= 1; off >>= 1) { s1 += __shfl_xor(s1, off); s2 += __shfl_xor(s2, off); }
  float mean = s1 * (1.f / D_MODEL);
  float var  = s2 * (1.f / D_MODEL) - mean * mean;
  float rstd = rsqrtf(var + 1e-5f);
  #pragma unroll
  for (int u = 0; u < 20; ++u) {
    int c = u * 16 + cl;
    sXb[rr * 328 + c] = f2bf((v[u] - mean) * rstd);
  }
  __syncthreads();

  // out GEMM: M=16, N=128, K=448; 4 waves x 2 o-tiles
  #pragma unroll
  for (int t = 0; t < 2; ++t) {
    int o = (wid * 2 + t) * 16 + lm;
    f32x4 acc = {};
    for (int kt = 0; kt < 14; ++kt) {
      bf16x8 a;
      if (kt < 4) a = *(const bf16x8*)&sQb[lm * 136 + kt * 32 + qd * 8];
      else        a = *(const bf16x8*)&sXb[lm * 328 + (kt - 4) * 32 + qd * 8];
      bf16x8 b = *(const bf16x8*)&nwc[(size_t)o * IN2 + kt * 32 + qd * 8];
      acc = MFMA16(a, b, acc);
    }
    float bz = f32r[F_B2 + o];
    #pragma unroll
    for (int r = 0; r < 4; ++r)
      out[(size_t)(n0 + qd * 4 + r) * HID + o] = fmaxf(acc[r] + bz, 0.f);
  }
}

extern "C" void kernel_launch(void* const* d_in, const int* in_sizes, int n_in,
                              void* d_out, int out_size, void* d_ws, size_t ws_size,
                              hipStream_t stream) {
  const float* nf   = (const float*)d_in[0];
  const float* ef   = (const float*)d_in[1];
  const float* dtp  = (const float*)d_in[2];
  const int*   nidx = (const int*)  d_in[3];
  const float* freq = (const float*)d_in[4];
  const float* ph   = (const float*)d_in[5];
  const float* wq   = (const float*)d_in[6];
  const float* wk   = (const float*)d_in[7];
  const float* wv   = (const float*)d_in[8];
  const float* fcw  = (const float*)d_in[9];
  const float* fcb  = (const float*)d_in[10];
  const float* lng  = (const float*)d_in[11];
  const float* lnb_ = (const float*)d_in[12];
  const float* nw   = (const float*)d_in[13];
  const float* nb   = (const float*)d_in[14];
  float* out = (float*)d_out;
  unsigned short* ws = (unsigned short*)d_ws;
  unsigned short* qkm = ws + WS_QKM;
  float* xacc = (float*)(ws + WS_X);

  prep1a  <<<226, 256, 0, stream>>>(nw, lng, fcb, ph, ws);
  prep1b  <<<160, 256, 0, stream>>>(wq, ph, nw, lnb_, nb, ws);
  prep_c0k<<<640, 256, 0, stream>>>(wk, ws);
  prep_wqk<<<80,  256, 0, stream>>>(wq, wk, ws);
  prep_wvf<<<800, 256, 0, stream>>>(fcw, wv, ws);
  tgat_qk   <<<2560, 256, 0, stream>>>(nf, ws, qkm);
  tgat_attn <<<8192, 256, 0, stream>>>(nf, ef, dtp, nidx, freq, ph, qkm);
  tgat_xgemm<<<512,  512, 0, stream>>>(ws, qkm, xacc);
  tgat_post2<<<512,  256, 0, stream>>>(nf, ws, xacc, out);
}

// Round 3
// 285.820 us; speedup vs baseline: 1.1379x; 1.1379x over previous
//
#include <hip/hip_runtime.h>
#include <math.h>

#define LNB      32
#define NODE_IN  128
#define EDGE_IN  64
#define TIME_D   128
#define D_MODEL  320
#define N_HEAD   8
#define D_K      64
#define NHD      512
#define HID      128
#define IN2      448
#define N_DSTN   8192

typedef __attribute__((ext_vector_type(8))) short bf16x8;
typedef __attribute__((ext_vector_type(4))) float f32x4;
#define MFMA16(a,b,c) __builtin_amdgcn_mfma_f32_16x16x32_bf16(a,b,c,0,0,0)

// ---- ws layout (elements of unsigned short) ----
#define WS_QKM   0            // 8192*2560 : qk (h-major) -> mbar (d*8+h layout), in place
#define WS_WQK   20971520     // 2560*128  : folded wk@wq   (row-major [h*320+d][k])
#define WS_WVF   21299200     // 320*2560  : folded fcw@wv  ([c][d*8+h])
#define WS_NWC   22118400     // 128*448   : [nw1 | nw2*lng]
#define WS_F32   22175744     // 3520 floats
#define WS_X     22182784     // 8192*320 f32 accumulation buffer
// total = 27,425,664 shorts = 54.9 MB

#define F_C0     0            // 512
#define F_C0K    512          // 2560
#define F_CC     3072         // 320 : fcb + q-const residual
#define F_B2     3392         // 128 : nb + nw2@lnb

// native RTNE f32->bf16 (v_cvt_pk_bf16_f32 on gfx950) — bit-identical to manual RTNE
__device__ __forceinline__ unsigned short f2bf(float f) {
  __bf16 h = (__bf16)f;
  return __builtin_bit_cast(unsigned short, h);
}
__device__ __forceinline__ bf16x8 pack8(const float* v) {
  unsigned short b8[8];
  #pragma unroll
  for (int j = 0; j < 8; ++j) b8[j] = f2bf(v[j]);
  return *(const bf16x8*)b8;
}

// =================== prep1a: elementwise folds ==============================
__global__ __launch_bounds__(256)
void prep1a(const float* __restrict__ nw, const float* __restrict__ lng,
            const float* __restrict__ fcb, const float* __restrict__ ph,
            unsigned short* __restrict__ ws)
{
  int i = blockIdx.x * 256 + threadIdx.x;
  unsigned short* nwc = ws + WS_NWC;
  float* f32r = (float*)(ws + WS_F32);
  if (i < 16384) {                       // nw1 cast
    int o = i >> 7, k = i & 127;
    nwc[o * IN2 + k] = f2bf(nw[(size_t)o * IN2 + k]);
  } else if (i < 57344) {                // nw2g = nw2 * lng
    int j = i - 16384, o = j / 320, c = j - o * 320;
    nwc[o * IN2 + 128 + c] = f2bf(nw[(size_t)o * IN2 + 128 + c] * lng[c]);
  } else if (i < 57664) {                // cc[c] = fcb + q-const
    int c = i - 57344;
    f32r[F_CC + c] = fcb[c] + (c >= 192 ? __cosf(ph[c - 192]) : 0.f);
  }
}

// =================== prep1b: c0 (512 waves) + b2 (128 waves) ===============
__global__ __launch_bounds__(256)
void prep1b(const float* __restrict__ wq, const float* __restrict__ ph,
            const float* __restrict__ nw, const float* __restrict__ lnb_,
            const float* __restrict__ nb, unsigned short* __restrict__ ws)
{
  float* f32r = (float*)(ws + WS_F32);
  int gw = (blockIdx.x * 256 + threadIdx.x) >> 6;
  int ln = threadIdx.x & 63;
  if (gw < 512) {                        // c0[j] = cos(ph) . wq[j][192:]
    float s = __cosf(ph[ln])      * wq[(size_t)gw * D_MODEL + 192 + ln]
            + __cosf(ph[ln + 64]) * wq[(size_t)gw * D_MODEL + 256 + ln];
    #pragma unroll
    for (int off = 32; off >= 1; off >>= 1) s += __shfl_xor(s, off);
    if (ln == 0) f32r[F_C0 + gw] = s;
  } else {                               // b2[o] = nb + nw2 . lnb
    int o = gw - 512;
    float s = 0.f;
    #pragma unroll
    for (int k = 0; k < 5; ++k) {
      int c = ln + 64 * k;
      s += nw[(size_t)o * IN2 + 128 + c] * lnb_[c];
    }
    #pragma unroll
    for (int off = 32; off >= 1; off >>= 1) s += __shfl_xor(s, off);
    if (ln == 0) f32r[F_B2 + o] = nb[o] + s;
  }
}

// =================== prep_c0k: one wave per hd ==============================
__global__ __launch_bounds__(256)
void prep_c0k(const float* __restrict__ wk, unsigned short* __restrict__ ws)
{
  float* f32r = (float*)(ws + WS_F32);
  int gw = (blockIdx.x * 256 + threadIdx.x) >> 6;   // 0..2559
  int ln = threadIdx.x & 63;
  int h = gw / 320, d = gw - h * 320;
  float s = f32r[F_C0 + h * 64 + ln] * wk[(size_t)(h * 64 + ln) * D_MODEL + d];
  #pragma unroll
  for (int off = 32; off >= 1; off >>= 1) s += __shfl_xor(s, off);
  if (ln == 0) f32r[F_C0K + gw] = s;
}

// =================== prep_wqk: LDS-tiled fold (80 blocks) ===================
__global__ __launch_bounds__(256)
void prep_wqk(const float* __restrict__ wq, const float* __restrict__ wk,
              unsigned short* __restrict__ ws)
{
  __shared__ float sQw[64 * 128];
  __shared__ float sKw[64 * 32];
  int h = blockIdx.x / 10, d0 = (blockIdx.x - h * 10) * 32;
  int tid = threadIdx.x;
  #pragma unroll 4
  for (int it = 0; it < 32; ++it) {
    int idx = it * 256 + tid;
    int r = idx >> 7, c = idx & 127;
    sQw[idx] = wq[(size_t)(h * 64 + r) * D_MODEL + c];
  }
  #pragma unroll
  for (int it = 0; it < 8; ++it) {
    int idx = it * 256 + tid;
    int r = idx >> 5, c = idx & 31;
    sKw[idx] = wk[(size_t)(h * 64 + r) * D_MODEL + d0 + c];
  }
  __syncthreads();
  int di = tid >> 3, k0 = (tid & 7) * 16;
  float acc[16] = {};
  for (int dk = 0; dk < 64; ++dk) {
    float w = sKw[dk * 32 + di];
    #pragma unroll
    for (int j = 0; j < 16; ++j) acc[j] += w * sQw[dk * 128 + k0 + j];
  }
  unsigned short* dst = ws + WS_WQK + (size_t)(h * 320 + d0 + di) * 128 + k0;
  #pragma unroll
  for (int j = 0; j < 16; ++j) dst[j] = f2bf(acc[j]);
}

// =================== prep_wvf: LDS-tiled fold (800 blocks) ==================
// wvf[c][d*8+h] = sum_jj fcw[c][h*64+jj] * wv[h*64+jj][d]
__global__ __launch_bounds__(256)
void prep_wvf(const float* __restrict__ fcw, const float* __restrict__ wv,
              unsigned short* __restrict__ ws)
{
  __shared__ float sF[32 * 64];
  __shared__ float sW[64 * 32];
  int b = blockIdx.x;
  int h = b / 100, r2 = b - h * 100;
  int ct = r2 / 10;
  int c0 = ct * 32, d0 = (r2 - ct * 10) * 32;
  int tid = threadIdx.x;
  #pragma unroll
  for (int it = 0; it < 8; ++it) {
    int idx = it * 256 + tid;
    int i = idx >> 6, jj = idx & 63;
    sF[idx] = fcw[(size_t)(c0 + i) * NHD + h * 64 + jj];
  }
  #pragma unroll
  for (int it = 0; it < 8; ++it) {
    int idx = it * 256 + tid;
    int jj = idx >> 5, i = idx & 31;
    sW[idx] = wv[(size_t)(h * 64 + jj) * D_MODEL + d0 + i];
  }
  __syncthreads();
  int ci = tid >> 3, dj0 = (tid & 7) * 4;
  float acc[4] = {};
  for (int jj = 0; jj < 64; ++jj) {
    float f = sF[ci * 64 + jj];
    #pragma unroll
    for (int k = 0; k < 4; ++k) acc[k] += f * sW[jj * 32 + dj0 + k];
  }
  unsigned short* wvf = ws + WS_WVF;
  #pragma unroll
  for (int k = 0; k < 4; ++k)
    wvf[(size_t)(c0 + ci) * 2560 + (size_t)(d0 + dj0 + k) * 8 + h] = f2bf(acc[k]);
}

// =================== K1: qk = nf @ wqk^T + c0k  (h-major layout) ============
__global__ __launch_bounds__(256, 6)
void tgat_qk(const float* __restrict__ nf, const unsigned short* __restrict__ ws,
             unsigned short* __restrict__ qkm)
{
  __shared__ alignas(16) unsigned short sA[64 * 136];
  const int tid = threadIdx.x, wid = tid >> 6, lane = tid & 63, qd = lane >> 4, lm = lane & 15;
  const int mt_blk = blockIdx.x / 20, nt_blk = blockIdx.x - mt_blk * 20;
  const int n0 = mt_blk * 64, c0 = nt_blk * 128;
  const unsigned short* wqk = ws + WS_WQK;
  const float* f32r = (const float*)(ws + WS_F32);

  { // stage A: 64 x 128 bf16 (coalesced)
    int n = tid >> 2, k0 = (tid & 3) * 32;
    const float4* src = (const float4*)(nf + (size_t)(n0 + n) * NODE_IN + k0);
    #pragma unroll
    for (int q = 0; q < 4; ++q) {
      float4 f0 = src[2 * q], f1 = src[2 * q + 1];
      float v[8] = {f0.x, f0.y, f0.z, f0.w, f1.x, f1.y, f1.z, f1.w};
      *(bf16x8*)&sA[n * 136 + k0 + q * 8] = pack8(v);
    }
  }
  __syncthreads();

  f32x4 acc[2][4] = {};
  for (int kt = 0; kt < 4; ++kt) {
    bf16x8 a[4];
    #pragma unroll
    for (int mt = 0; mt < 4; ++mt)
      a[mt] = *(const bf16x8*)&sA[(mt * 16 + lm) * 136 + kt * 32 + qd * 8];
    #pragma unroll
    for (int t = 0; t < 2; ++t) {
      int cg = c0 + (2 * wid + t) * 16 + lm;
      bf16x8 b = *(const bf16x8*)&wqk[(size_t)cg * 128 + kt * 32 + qd * 8];
      #pragma unroll
      for (int mt = 0; mt < 4; ++mt) acc[t][mt] = MFMA16(a[mt], b, acc[t][mt]);
    }
  }
  #pragma unroll
  for (int t = 0; t < 2; ++t) {
    int cg = c0 + (2 * wid + t) * 16 + lm;
    float ck = f32r[F_C0K + cg];
    #pragma unroll
    for (int mt = 0; mt < 4; ++mt)
      #pragma unroll
      for (int r = 0; r < 4; ++r)
        qkm[(size_t)(n0 + mt * 16 + qd * 4 + r) * 2560 + cg] = f2bf(acc[t][mt][r] + ck);
  }
}

// =================== K2: attention (one barrier before scores) ==============
__global__ __launch_bounds__(256, 6)
void tgat_attn(const float* __restrict__ nf, const float* __restrict__ ef,
               const float* __restrict__ dtp, const int* __restrict__ nidx,
               const float* __restrict__ freq, const float* __restrict__ ph,
               unsigned short* __restrict__ qkm)
{
  __shared__ alignas(16) unsigned short sM[LNB * 328];    // 21 KB
  __shared__ alignas(16) unsigned short sATT[16 * 40];    // 1.25 KB

  const int tid = threadIdx.x;
  const int wid = tid >> 6, lane = tid & 63, qd = lane >> 4, lm = lane & 15;
  const int n = blockIdx.x;
  unsigned short* qn = qkm + (size_t)n * 2560;

  // ---- m build: thread -> (l = g&31, 8 consecutive d); tables direct from L2
  #pragma unroll 1
  for (int it = 0; it < 5; ++it) {
    int g = it * 256 + tid;
    int l = g & 31, dg = g >> 5;
    int d0 = dg * 8;
    float v[8];
    if (dg < 16) {
      int ni = nidx[n * 16 + (l >> 1)];
      const float4* src = (const float4*)(nf + (size_t)ni * NODE_IN + d0);
      float4 f0 = src[0], f1 = src[1];
      v[0]=f0.x; v[1]=f0.y; v[2]=f0.z; v[3]=f0.w; v[4]=f1.x; v[5]=f1.y; v[6]=f1.z; v[7]=f1.w;
    } else if (dg < 24) {
      const float4* src = (const float4*)(ef + ((size_t)n * LNB + l) * EDGE_IN + (d0 - NODE_IN));
      float4 f0 = src[0], f1 = src[1];
      v[0]=f0.x; v[1]=f0.y; v[2]=f0.z; v[3]=f0.w; v[4]=f1.x; v[5]=f1.y; v[6]=f1.z; v[7]=f1.w;
    } else {
      int dd = d0 - 192;
      float dt = dtp[(size_t)n * LNB + l];
      const float4* fq = (const float4*)(freq + dd);
      const float4* pp = (const float4*)(ph + dd);
      float4 q0 = fq[0], q1 = fq[1], p0 = pp[0], p1 = pp[1];
      v[0] = __cosf(dt * q0.x + p0.x); v[1] = __cosf(dt * q0.y + p0.y);
      v[2] = __cosf(dt * q0.z + p0.z); v[3] = __cosf(dt * q0.w + p0.w);
      v[4] = __cosf(dt * q1.x + p1.x); v[5] = __cosf(dt * q1.y + p1.y);
      v[6] = __cosf(dt * q1.z + p1.z); v[7] = __cosf(dt * q1.w + p1.w);
    }
    *(bf16x8*)&sM[l * 328 + d0] = pack8(v);
  }

  // wave0: issue qk B-frag loads now — latency hides under the barrier wait
  bf16x8 qfrag[10];
  if (wid == 0) {
    #pragma unroll
    for (int kt = 0; kt < 10; ++kt) {
      qfrag[kt] = (bf16x8){0,0,0,0,0,0,0,0};
      if (lm < 8) qfrag[kt] = *(const bf16x8*)&qn[lm * 320 + kt * 32 + qd * 8];
    }
  }
  __syncthreads();                       // barrier 1: m ready

  // mbar tile ownership: wave0 -> 2 tiles, waves1-3 -> 6 each (20 total)
  const int tbeg = (wid == 0) ? 0 : 2 + (wid - 1) * 6;
  const int tcnt = (wid == 0) ? 2 : 6;
  bf16x8 afr[6];

  if (wid == 0) {
    // scores: D[l][h] = m @ qk^T / 8
    f32x4 acc0 = {}, acc1 = {};
    #pragma unroll
    for (int kt = 0; kt < 10; ++kt) {
      bf16x8 a0 = *(const bf16x8*)&sM[lm * 328 + kt * 32 + qd * 8];
      bf16x8 a1 = *(const bf16x8*)&sM[(16 + lm) * 328 + kt * 32 + qd * 8];
      acc0 = MFMA16(a0, qfrag[kt], acc0);
      acc1 = MFMA16(a1, qfrag[kt], acc1);
    }
    float s[8], e[8];
    #pragma unroll
    for (int r = 0; r < 4; ++r) { s[r] = acc0[r] * 0.125f; s[4 + r] = acc1[r] * 0.125f; }
    float mx = s[0];
    #pragma unroll
    for (int i = 1; i < 8; ++i) mx = fmaxf(mx, s[i]);
    mx = fmaxf(mx, __shfl_xor(mx, 16));
    mx = fmaxf(mx, __shfl_xor(mx, 32));
    float sum = 0.f;
    #pragma unroll
    for (int i = 0; i < 8; ++i) { e[i] = __expf(s[i] - mx); sum += e[i]; }
    sum += __shfl_xor(sum, 16);
    sum += __shfl_xor(sum, 32);
    float inv = 1.f / sum;
    #pragma unroll
    for (int i = 0; i < 8; ++i) {
      int l = (i < 4) ? (qd * 4 + i) : (16 + qd * 4 + (i - 4));
      sATT[lm * 40 + l] = f2bf(e[i] * inv);
    }
  } else {
    // waves 1-3: prefetch transposed-m A-frags for my 6 tiles (overlaps softmax)
    #pragma unroll
    for (int u = 0; u < 6; ++u) {
      int d = (tbeg + u) * 16 + lm;
      unsigned short a8[8];
      #pragma unroll
      for (int j = 0; j < 8; ++j) a8[j] = sM[(qd * 8 + j) * 328 + d];
      afr[u] = *(const bf16x8*)a8;
    }
  }
  __syncthreads();                       // barrier 2: sATT ready

  if (wid == 0) {                        // wave0 fetches its 2 tiles now
    #pragma unroll
    for (int u = 0; u < 2; ++u) {
      int d = u * 16 + lm;
      unsigned short a8[8];
      #pragma unroll
      for (int j = 0; j < 8; ++j) a8[j] = sM[(qd * 8 + j) * 328 + d];
      afr[u] = *(const bf16x8*)a8;
    }
  }
  bf16x8 batt = *(const bf16x8*)&sATT[lm * 40 + qd * 8];
  #pragma unroll
  for (int u = 0; u < 6; ++u) {
    if (u < tcnt) {                      // wave-uniform guard
      int dtile = tbeg + u;
      f32x4 acc = {};
      acc = MFMA16(afr[u], batt, acc);
      if (lm < 8) {
        #pragma unroll
        for (int r = 0; r < 4; ++r)
          qn[(dtile * 16 + qd * 4 + r) * 8 + lm] = f2bf(acc[r]);
      }
    }
  }
}

// =================== K3a: x = mbar @ wvf^T (barrier-free reg streaming) =====
// 256 blocks x 512 thr. Block owns 32 rows x all 320 cols.
// 8 waves = 4 col-slices (cs) x 2 k-halves (kh); wave accumulates its
// 32x80 tile over half-K (40 steps: 2 A-loads + 5 B-loads + 10 MFMA),
// A/B fragments loaded DIRECTLY global->reg (no LDS staging, no barriers
// in the K-loop — compiler pipelines loads via unroll). One barrier at the
// end merges k-halves through padded LDS; plain f32 stores, no atomics.
__global__ __launch_bounds__(512, 2)
void tgat_xgemm(const unsigned short* __restrict__ ws,
                const unsigned short* __restrict__ qkm, float* __restrict__ xacc)
{
  __shared__ float sRed[32 * 324];   // 41.5 KB, pad 320->324: 2-way max
  const int tid = threadIdx.x, wid = tid >> 6, lane = tid & 63;
  const int qd = lane >> 4, lm = lane & 15;
  const int kh = wid >> 2, cs = wid & 3;
  const int n0 = blockIdx.x * 32;
  const unsigned short* wvf = ws + WS_WVF;

  const unsigned short* A0 = qkm + (size_t)(n0 + lm) * 2560 + kh * 1280 + qd * 8;
  const unsigned short* A1 = A0 + (size_t)16 * 2560;
  const unsigned short* B0 = wvf + (size_t)(cs * 80 + lm) * 2560 + kh * 1280 + qd * 8;

  f32x4 acc[2][5] = {};
  #pragma unroll 4
  for (int kt = 0; kt < 40; ++kt) {
    bf16x8 a0 = *(const bf16x8*)(A0 + kt * 32);
    bf16x8 a1 = *(const bf16x8*)(A1 + kt * 32);
    #pragma unroll
    for (int u = 0; u < 5; ++u) {
      bf16x8 b = *(const bf16x8*)(B0 + (size_t)u * 16 * 2560 + kt * 32);
      acc[0][u] = MFMA16(a0, b, acc[0][u]);
      acc[1][u] = MFMA16(a1, b, acc[1][u]);
    }
  }

  if (kh == 1) {
    #pragma unroll
    for (int mt = 0; mt < 2; ++mt)
      #pragma unroll
      for (int u = 0; u < 5; ++u)
        #pragma unroll
        for (int r = 0; r < 4; ++r)
          sRed[(mt * 16 + qd * 4 + r) * 324 + cs * 80 + u * 16 + lm] = acc[mt][u][r];
  }
  __syncthreads();
  if (kh == 0) {
    #pragma unroll
    for (int mt = 0; mt < 2; ++mt)
      #pragma unroll
      for (int u = 0; u < 5; ++u)
        #pragma unroll
        for (int r = 0; r < 4; ++r) {
          int row = mt * 16 + qd * 4 + r, col = cs * 80 + u * 16 + lm;
          xacc[(size_t)(n0 + row) * 320 + col] = acc[mt][u][r] + sRed[row * 324 + col];
        }
  }
}

// =================== K3b: LN + out GEMM (512 blocks) ========================
__global__ __launch_bounds__(256, 4)
void tgat_post2(const float* __restrict__ nf, const unsigned short* __restrict__ ws,
                const float* __restrict__ xacc, float* __restrict__ out)
{
  __shared__ alignas(16) unsigned short sQb[16 * 136];
  __shared__ alignas(16) unsigned short sXb[16 * 328];
  const int tid = threadIdx.x, wid = tid >> 6, lane = tid & 63, qd = lane >> 4, lm = lane & 15;
  const int n0 = blockIdx.x * 16;
  const unsigned short* nwc = ws + WS_NWC;
  const float* f32r = (const float*)(ws + WS_F32);

  { // stage h_dst bf16
    int nn = tid >> 4, kk = (tid & 15) * 8;
    const float4* src = (const float4*)(nf + (size_t)(n0 + nn) * NODE_IN + kk);
    float4 f0 = src[0], f1 = src[1];
    float v8[8] = {f0.x, f0.y, f0.z, f0.w, f1.x, f1.y, f1.z, f1.w};
    *(bf16x8*)&sQb[nn * 136 + kk] = pack8(v8);
  }
  // LN: thread owns (row rr, cols cl+16u); reduce over the 16-lane row group
  const int rr = tid >> 4, cl = tid & 15;
  float v[20], s1 = 0.f, s2 = 0.f;
  #pragma unroll
  for (int u = 0; u < 20; ++u) {
    int c = u * 16 + cl;
    float x = xacc[(size_t)(n0 + rr) * 320 + c] + f32r[F_CC + c];
    if (c < 128) x += nf[(size_t)(n0 + rr) * NODE_IN + c];
    v[u] = x; s1 += x; s2 += x * x;
  }
  #pragma unroll
  for (int off = 8; off >= 1; off >>= 1) { s1 += __shfl_xor(s1, off); s2 += __shfl_xor(s2, off); }
  float mean = s1 * (1.f / D_MODEL);
  float var  = s2 * (1.f / D_MODEL) - mean * mean;
  float rstd = rsqrtf(var + 1e-5f);
  #pragma unroll
  for (int u = 0; u < 20; ++u) {
    int c = u * 16 + cl;
    sXb[rr * 328 + c] = f2bf((v[u] - mean) * rstd);
  }
  __syncthreads();

  // out GEMM: M=16, N=128, K=448; 4 waves x 2 o-tiles
  #pragma unroll
  for (int t = 0; t < 2; ++t) {
    int o = (wid * 2 + t) * 16 + lm;
    f32x4 acc = {};
    for (int kt = 0; kt < 14; ++kt) {
      bf16x8 a;
      if (kt < 4) a = *(const bf16x8*)&sQb[lm * 136 + kt * 32 + qd * 8];
      else        a = *(const bf16x8*)&sXb[lm * 328 + (kt - 4) * 32 + qd * 8];
      bf16x8 b = *(const bf16x8*)&nwc[(size_t)o * IN2 + kt * 32 + qd * 8];
      acc = MFMA16(a, b, acc);
    }
    float bz = f32r[F_B2 + o];
    #pragma unroll
    for (int r = 0; r < 4; ++r)
      out[(size_t)(n0 + qd * 4 + r) * HID + o] = fmaxf(acc[r] + bz, 0.f);
  }
}

extern "C" void kernel_launch(void* const* d_in, const int* in_sizes, int n_in,
                              void* d_out, int out_size, void* d_ws, size_t ws_size,
                              hipStream_t stream) {
  const float* nf   = (const float*)d_in[0];
  const float* ef   = (const float*)d_in[1];
  const float* dtp  = (const float*)d_in[2];
  const int*   nidx = (const int*)  d_in[3];
  const float* freq = (const float*)d_in[4];
  const float* ph   = (const float*)d_in[5];
  const float* wq   = (const float*)d_in[6];
  const float* wk   = (const float*)d_in[7];
  const float* wv   = (const float*)d_in[8];
  const float* fcw  = (const float*)d_in[9];
  const float* fcb  = (const float*)d_in[10];
  const float* lng  = (const float*)d_in[11];
  const float* lnb_ = (const float*)d_in[12];
  const float* nw   = (const float*)d_in[13];
  const float* nb   = (const float*)d_in[14];
  float* out = (float*)d_out;
  unsigned short* ws = (unsigned short*)d_ws;
  unsigned short* qkm = ws + WS_QKM;
  float* xacc = (float*)(ws + WS_X);

  prep1a  <<<226, 256, 0, stream>>>(nw, lng, fcb, ph, ws);
  prep1b  <<<160, 256, 0, stream>>>(wq, ph, nw, lnb_, nb, ws);
  prep_c0k<<<640, 256, 0, stream>>>(wk, ws);
  prep_wqk<<<80,  256, 0, stream>>>(wq, wk, ws);
  prep_wvf<<<800, 256, 0, stream>>>(fcw, wv, ws);
  tgat_qk   <<<2560, 256, 0, stream>>>(nf, ws, qkm);
  tgat_attn <<<8192, 256, 0, stream>>>(nf, ef, dtp, nidx, freq, ph, qkm);
  tgat_xgemm<<<256,  512, 0, stream>>>(ws, qkm, xacc);
  tgat_post2<<<512,  256, 0, stream>>>(nf, ws, xacc, out);
}

// Round 4
// 270.275 us; speedup vs baseline: 1.2034x; 1.0575x over previous
//
#include <hip/hip_runtime.h>
#include <math.h>

#define LNB      32
#define NODE_IN  128
#define EDGE_IN  64
#define TIME_D   128
#define D_MODEL  320
#define N_HEAD   8
#define D_K      64
#define NHD      512
#define HID      128
#define IN2      448
#define N_DSTN   8192

typedef __attribute__((ext_vector_type(8))) short bf16x8;
typedef __attribute__((ext_vector_type(4))) float f32x4;
#define MFMA16(a,b,c) __builtin_amdgcn_mfma_f32_16x16x32_bf16(a,b,c,0,0,0)

// ---- ws layout (elements of unsigned short) ----
#define WS_QKM   0            // 8192*2560 : qk (h-major) -> mbar (d*8+h layout), in place
#define WS_WQK   20971520     // 2560*128  : folded wk@wq   (row-major [h*320+d][k])
#define WS_WVF   21299200     // 320*2560  : folded fcw@wv  ([c][d*8+h])
#define WS_NWC   22118400     // 128*448   : [nw1 | nw2*lng]
#define WS_F32   22175744     // 3520 floats
// (x-accumulator eliminated: LN+out GEMM fused into the x GEMM kernel)

#define F_C0     0            // 512
#define F_C0K    512          // 2560
#define F_CC     3072         // 320 : fcb + q-const residual
#define F_B2     3392         // 128 : nb + nw2@lnb

// native RTNE f32->bf16 (v_cvt_pk_bf16_f32 on gfx950) — bit-identical to manual RTNE
__device__ __forceinline__ unsigned short f2bf(float f) {
  __bf16 h = (__bf16)f;
  return __builtin_bit_cast(unsigned short, h);
}
__device__ __forceinline__ bf16x8 pack8(const float* v) {
  unsigned short b8[8];
  #pragma unroll
  for (int j = 0; j < 8; ++j) b8[j] = f2bf(v[j]);
  return *(const bf16x8*)b8;
}

// =================== prep1a: elementwise folds ==============================
__global__ __launch_bounds__(256)
void prep1a(const float* __restrict__ nw, const float* __restrict__ lng,
            const float* __restrict__ fcb, const float* __restrict__ ph,
            unsigned short* __restrict__ ws)
{
  int i = blockIdx.x * 256 + threadIdx.x;
  unsigned short* nwc = ws + WS_NWC;
  float* f32r = (float*)(ws + WS_F32);
  if (i < 16384) {                       // nw1 cast
    int o = i >> 7, k = i & 127;
    nwc[o * IN2 + k] = f2bf(nw[(size_t)o * IN2 + k]);
  } else if (i < 57344) {                // nw2g = nw2 * lng
    int j = i - 16384, o = j / 320, c = j - o * 320;
    nwc[o * IN2 + 128 + c] = f2bf(nw[(size_t)o * IN2 + 128 + c] * lng[c]);
  } else if (i < 57664) {                // cc[c] = fcb + q-const
    int c = i - 57344;
    f32r[F_CC + c] = fcb[c] + (c >= 192 ? __cosf(ph[c - 192]) : 0.f);
  }
}

// =================== prep1b: c0 (512 waves) + b2 (128 waves) ===============
__global__ __launch_bounds__(256)
void prep1b(const float* __restrict__ wq, const float* __restrict__ ph,
            const float* __restrict__ nw, const float* __restrict__ lnb_,
            const float* __restrict__ nb, unsigned short* __restrict__ ws)
{
  float* f32r = (float*)(ws + WS_F32);
  int gw = (blockIdx.x * 256 + threadIdx.x) >> 6;
  int ln = threadIdx.x & 63;
  if (gw < 512) {                        // c0[j] = cos(ph) . wq[j][192:]
    float s = __cosf(ph[ln])      * wq[(size_t)gw * D_MODEL + 192 + ln]
            + __cosf(ph[ln + 64]) * wq[(size_t)gw * D_MODEL + 256 + ln];
    #pragma unroll
    for (int off = 32; off >= 1; off >>= 1) s += __shfl_xor(s, off);
    if (ln == 0) f32r[F_C0 + gw] = s;
  } else {                               // b2[o] = nb + nw2 . lnb
    int o = gw - 512;
    float s = 0.f;
    #pragma unroll
    for (int k = 0; k < 5; ++k) {
      int c = ln + 64 * k;
      s += nw[(size_t)o * IN2 + 128 + c] * lnb_[c];
    }
    #pragma unroll
    for (int off = 32; off >= 1; off >>= 1) s += __shfl_xor(s, off);
    if (ln == 0) f32r[F_B2 + o] = nb[o] + s;
  }
}

// =================== prep_c0k: one wave per hd ==============================
__global__ __launch_bounds__(256)
void prep_c0k(const float* __restrict__ wk, unsigned short* __restrict__ ws)
{
  float* f32r = (float*)(ws + WS_F32);
  int gw = (blockIdx.x * 256 + threadIdx.x) >> 6;   // 0..2559
  int ln = threadIdx.x & 63;
  int h = gw / 320, d = gw - h * 320;
  float s = f32r[F_C0 + h * 64 + ln] * wk[(size_t)(h * 64 + ln) * D_MODEL + d];
  #pragma unroll
  for (int off = 32; off >= 1; off >>= 1) s += __shfl_xor(s, off);
  if (ln == 0) f32r[F_C0K + gw] = s;
}

// =================== prep_wqk: LDS-tiled fold (80 blocks) ===================
__global__ __launch_bounds__(256)
void prep_wqk(const float* __restrict__ wq, const float* __restrict__ wk,
              unsigned short* __restrict__ ws)
{
  __shared__ float sQw[64 * 128];
  __shared__ float sKw[64 * 32];
  int h = blockIdx.x / 10, d0 = (blockIdx.x - h * 10) * 32;
  int tid = threadIdx.x;
  #pragma unroll 4
  for (int it = 0; it < 32; ++it) {
    int idx = it * 256 + tid;
    int r = idx >> 7, c = idx & 127;
    sQw[idx] = wq[(size_t)(h * 64 + r) * D_MODEL + c];
  }
  #pragma unroll
  for (int it = 0; it < 8; ++it) {
    int idx = it * 256 + tid;
    int r = idx >> 5, c = idx & 31;
    sKw[idx] = wk[(size_t)(h * 64 + r) * D_MODEL + d0 + c];
  }
  __syncthreads();
  int di = tid >> 3, k0 = (tid & 7) * 16;
  float acc[16] = {};
  for (int dk = 0; dk < 64; ++dk) {
    float w = sKw[dk * 32 + di];
    #pragma unroll
    for (int j = 0; j < 16; ++j) acc[j] += w * sQw[dk * 128 + k0 + j];
  }
  unsigned short* dst = ws + WS_WQK + (size_t)(h * 320 + d0 + di) * 128 + k0;
  #pragma unroll
  for (int j = 0; j < 16; ++j) dst[j] = f2bf(acc[j]);
}

// =================== prep_wvf: LDS-tiled fold (800 blocks) ==================
// wvf[c][d*8+h] = sum_jj fcw[c][h*64+jj] * wv[h*64+jj][d]
__global__ __launch_bounds__(256)
void prep_wvf(const float* __restrict__ fcw, const float* __restrict__ wv,
              unsigned short* __restrict__ ws)
{
  __shared__ float sF[32 * 64];
  __shared__ float sW[64 * 32];
  int b = blockIdx.x;
  int h = b / 100, r2 = b - h * 100;
  int ct = r2 / 10;
  int c0 = ct * 32, d0 = (r2 - ct * 10) * 32;
  int tid = threadIdx.x;
  #pragma unroll
  for (int it = 0; it < 8; ++it) {
    int idx = it * 256 + tid;
    int i = idx >> 6, jj = idx & 63;
    sF[idx] = fcw[(size_t)(c0 + i) * NHD + h * 64 + jj];
  }
  #pragma unroll
  for (int it = 0; it < 8; ++it) {
    int idx = it * 256 + tid;
    int jj = idx >> 5, i = idx & 31;
    sW[idx] = wv[(size_t)(h * 64 + jj) * D_MODEL + d0 + i];
  }
  __syncthreads();
  int ci = tid >> 3, dj0 = (tid & 7) * 4;
  float acc[4] = {};
  for (int jj = 0; jj < 64; ++jj) {
    float f = sF[ci * 64 + jj];
    #pragma unroll
    for (int k = 0; k < 4; ++k) acc[k] += f * sW[jj * 32 + dj0 + k];
  }
  unsigned short* wvf = ws + WS_WVF;
  #pragma unroll
  for (int k = 0; k < 4; ++k)
    wvf[(size_t)(c0 + ci) * 2560 + (size_t)(d0 + dj0 + k) * 8 + h] = f2bf(acc[k]);
}

// =================== K1: qk = nf @ wqk^T + c0k  (h-major layout) ============
__global__ __launch_bounds__(256, 6)
void tgat_qk(const float* __restrict__ nf, const unsigned short* __restrict__ ws,
             unsigned short* __restrict__ qkm)
{
  __shared__ alignas(16) unsigned short sA[64 * 136];
  const int tid = threadIdx.x, wid = tid >> 6, lane = tid & 63, qd = lane >> 4, lm = lane & 15;
  const int mt_blk = blockIdx.x / 20, nt_blk = blockIdx.x - mt_blk * 20;
  const int n0 = mt_blk * 64, c0 = nt_blk * 128;
  const unsigned short* wqk = ws + WS_WQK;
  const float* f32r = (const float*)(ws + WS_F32);

  { // stage A: 64 x 128 bf16 (coalesced)
    int n = tid >> 2, k0 = (tid & 3) * 32;
    const float4* src = (const float4*)(nf + (size_t)(n0 + n) * NODE_IN + k0);
    #pragma unroll
    for (int q = 0; q < 4; ++q) {
      float4 f0 = src[2 * q], f1 = src[2 * q + 1];
      float v[8] = {f0.x, f0.y, f0.z, f0.w, f1.x, f1.y, f1.z, f1.w};
      *(bf16x8*)&sA[n * 136 + k0 + q * 8] = pack8(v);
    }
  }
  __syncthreads();

  f32x4 acc[2][4] = {};
  for (int kt = 0; kt < 4; ++kt) {
    bf16x8 a[4];
    #pragma unroll
    for (int mt = 0; mt < 4; ++mt)
      a[mt] = *(const bf16x8*)&sA[(mt * 16 + lm) * 136 + kt * 32 + qd * 8];
    #pragma unroll
    for (int t = 0; t < 2; ++t) {
      int cg = c0 + (2 * wid + t) * 16 + lm;
      bf16x8 b = *(const bf16x8*)&wqk[(size_t)cg * 128 + kt * 32 + qd * 8];
      #pragma unroll
      for (int mt = 0; mt < 4; ++mt) acc[t][mt] = MFMA16(a[mt], b, acc[t][mt]);
    }
  }
  #pragma unroll
  for (int t = 0; t < 2; ++t) {
    int cg = c0 + (2 * wid + t) * 16 + lm;
    float ck = f32r[F_C0K + cg];
    #pragma unroll
    for (int mt = 0; mt < 4; ++mt)
      #pragma unroll
      for (int r = 0; r < 4; ++r)
        qkm[(size_t)(n0 + mt * 16 + qd * 4 + r) * 2560 + cg] = f2bf(acc[t][mt][r] + ck);
  }
}

// =================== K2: attention (one barrier before scores) ==============
__global__ __launch_bounds__(256, 6)
void tgat_attn(const float* __restrict__ nf, const float* __restrict__ ef,
               const float* __restrict__ dtp, const int* __restrict__ nidx,
               const float* __restrict__ freq, const float* __restrict__ ph,
               unsigned short* __restrict__ qkm)
{
  __shared__ alignas(16) unsigned short sM[LNB * 328];    // 21 KB
  __shared__ alignas(16) unsigned short sATT[16 * 40];    // 1.25 KB

  const int tid = threadIdx.x;
  const int wid = tid >> 6, lane = tid & 63, qd = lane >> 4, lm = lane & 15;
  const int n = blockIdx.x;
  unsigned short* qn = qkm + (size_t)n * 2560;

  // ---- m build: thread -> (l = g&31, 8 consecutive d); tables direct from L2
  #pragma unroll 1
  for (int it = 0; it < 5; ++it) {
    int g = it * 256 + tid;
    int l = g & 31, dg = g >> 5;
    int d0 = dg * 8;
    float v[8];
    if (dg < 16) {
      int ni = nidx[n * 16 + (l >> 1)];
      const float4* src = (const float4*)(nf + (size_t)ni * NODE_IN + d0);
      float4 f0 = src[0], f1 = src[1];
      v[0]=f0.x; v[1]=f0.y; v[2]=f0.z; v[3]=f0.w; v[4]=f1.x; v[5]=f1.y; v[6]=f1.z; v[7]=f1.w;
    } else if (dg < 24) {
      const float4* src = (const float4*)(ef + ((size_t)n * LNB + l) * EDGE_IN + (d0 - NODE_IN));
      float4 f0 = src[0], f1 = src[1];
      v[0]=f0.x; v[1]=f0.y; v[2]=f0.z; v[3]=f0.w; v[4]=f1.x; v[5]=f1.y; v[6]=f1.z; v[7]=f1.w;
    } else {
      int dd = d0 - 192;
      float dt = dtp[(size_t)n * LNB + l];
      const float4* fq = (const float4*)(freq + dd);
      const float4* pp = (const float4*)(ph + dd);
      float4 q0 = fq[0], q1 = fq[1], p0 = pp[0], p1 = pp[1];
      v[0] = __cosf(dt * q0.x + p0.x); v[1] = __cosf(dt * q0.y + p0.y);
      v[2] = __cosf(dt * q0.z + p0.z); v[3] = __cosf(dt * q0.w + p0.w);
      v[4] = __cosf(dt * q1.x + p1.x); v[5] = __cosf(dt * q1.y + p1.y);
      v[6] = __cosf(dt * q1.z + p1.z); v[7] = __cosf(dt * q1.w + p1.w);
    }
    *(bf16x8*)&sM[l * 328 + d0] = pack8(v);
  }

  // wave0: issue qk B-frag loads now — latency hides under the barrier wait
  bf16x8 qfrag[10];
  if (wid == 0) {
    #pragma unroll
    for (int kt = 0; kt < 10; ++kt) {
      qfrag[kt] = (bf16x8){0,0,0,0,0,0,0,0};
      if (lm < 8) qfrag[kt] = *(const bf16x8*)&qn[lm * 320 + kt * 32 + qd * 8];
    }
  }
  __syncthreads();                       // barrier 1: m ready

  // mbar tile ownership: wave0 -> 2 tiles, waves1-3 -> 6 each (20 total)
  const int tbeg = (wid == 0) ? 0 : 2 + (wid - 1) * 6;
  const int tcnt = (wid == 0) ? 2 : 6;
  bf16x8 afr[6];

  if (wid == 0) {
    // scores: D[l][h] = m @ qk^T / 8
    f32x4 acc0 = {}, acc1 = {};
    #pragma unroll
    for (int kt = 0; kt < 10; ++kt) {
      bf16x8 a0 = *(const bf16x8*)&sM[lm * 328 + kt * 32 + qd * 8];
      bf16x8 a1 = *(const bf16x8*)&sM[(16 + lm) * 328 + kt * 32 + qd * 8];
      acc0 = MFMA16(a0, qfrag[kt], acc0);
      acc1 = MFMA16(a1, qfrag[kt], acc1);
    }
    float s[8], e[8];
    #pragma unroll
    for (int r = 0; r < 4; ++r) { s[r] = acc0[r] * 0.125f; s[4 + r] = acc1[r] * 0.125f; }
    float mx = s[0];
    #pragma unroll
    for (int i = 1; i < 8; ++i) mx = fmaxf(mx, s[i]);
    mx = fmaxf(mx, __shfl_xor(mx, 16));
    mx = fmaxf(mx, __shfl_xor(mx, 32));
    float sum = 0.f;
    #pragma unroll
    for (int i = 0; i < 8; ++i) { e[i] = __expf(s[i] - mx); sum += e[i]; }
    sum += __shfl_xor(sum, 16);
    sum += __shfl_xor(sum, 32);
    float inv = 1.f / sum;
    #pragma unroll
    for (int i = 0; i < 8; ++i) {
      int l = (i < 4) ? (qd * 4 + i) : (16 + qd * 4 + (i - 4));
      sATT[lm * 40 + l] = f2bf(e[i] * inv);
    }
  } else {
    // waves 1-3: prefetch transposed-m A-frags for my 6 tiles (overlaps softmax)
    #pragma unroll
    for (int u = 0; u < 6; ++u) {
      int d = (tbeg + u) * 16 + lm;
      unsigned short a8[8];
      #pragma unroll
      for (int j = 0; j < 8; ++j) a8[j] = sM[(qd * 8 + j) * 328 + d];
      afr[u] = *(const bf16x8*)a8;
    }
  }
  __syncthreads();                       // barrier 2: sATT ready

  if (wid == 0) {                        // wave0 fetches its 2 tiles now
    #pragma unroll
    for (int u = 0; u < 2; ++u) {
      int d = u * 16 + lm;
      unsigned short a8[8];
      #pragma unroll
      for (int j = 0; j < 8; ++j) a8[j] = sM[(qd * 8 + j) * 328 + d];
      afr[u] = *(const bf16x8*)a8;
    }
  }
  bf16x8 batt = *(const bf16x8*)&sATT[lm * 40 + qd * 8];
  #pragma unroll
  for (int u = 0; u < 6; ++u) {
    if (u < tcnt) {                      // wave-uniform guard
      int dtile = tbeg + u;
      f32x4 acc = {};
      acc = MFMA16(afr[u], batt, acc);
      if (lm < 8) {
        #pragma unroll
        for (int r = 0; r < 4; ++r)
          qn[(dtile * 16 + qd * 4 + r) * 8 + lm] = f2bf(acc[r]);
      }
    }
  }
}

// =================== K3: fused x-GEMM + LN + out-GEMM =======================
// 256 blocks x 512 thr. Block = 32 rows x 320 cols, full K=2560.
// 8 waves = 4 col-slices (cs) x 2 k-halves (kh). K split into 4 phases of
// 320k (both halves staged per phase: 40 KB, double-buffered). Per phase:
// issue next chunk's global loads into regs EARLY, compute 10 k-steps
// (B-frags rolled 3-deep in regs), then ds_write + one barrier — stage
// latency hides under the ~700-cyc compute phase. A rows read once per
// block (shared via LDS). XOR swizzle kills the stride-640B bank conflict.
// Epilogue: kh-merge through LDS f32 (overlay), LN, out GEMM (ex-post2).
__global__ __launch_bounds__(512, 1)
void tgat_xgemm(const float* __restrict__ nf, const unsigned short* __restrict__ ws,
                const unsigned short* __restrict__ qkm, float* __restrict__ out)
{
  __shared__ alignas(16) unsigned short sAb[2 * 20480];   // 80 KB (2 x 40 KB chunk)
  __shared__ alignas(16) unsigned short sXb[32 * 328];    // 21 KB
  __shared__ alignas(16) unsigned short sQb[32 * 136];    // 8.7 KB
  const int tid = threadIdx.x, wid = tid >> 6, lane = tid & 63;
  const int qd = lane >> 4, lm = lane & 15;
  const int kh = wid >> 2, cs = wid & 3;
  const int n0 = blockIdx.x * 32;
  const unsigned short* wvf = ws + WS_WVF;
  const unsigned short* nwc = ws + WS_NWC;
  const float* f32r = (const float*)(ws + WS_F32);

  // ---- staging helpers (thread covers 5 x 16B; layout [kh2][r][320k swz]) --
  // byte offset in chunk: o = i*8192 + tid*16 ; kh2 = o/20480 ; r = o2/640 ;
  // b = o2%640 ; LDS idx (ushort) = kh2*10240 + r*320 + ((b ^ ((r&7)<<4))>>1)
  bf16x8 st[5];
  #define STAGE_LOAD(p) {                                                      \
    _Pragma("unroll")                                                          \
    for (int i = 0; i < 5; ++i) {                                              \
      int o = i * 8192 + tid * 16;                                             \
      int kh2 = o / 20480, o2 = o - kh2 * 20480;                               \
      int r = o2 / 640, b = o2 - r * 640;                                      \
      st[i] = *(const bf16x8*)(qkm + (size_t)(n0 + r) * 2560 + kh2 * 1280      \
                               + (p) * 320 + (b >> 1));                        \
    } }
  #define STAGE_WRITE(q) {                                                     \
    unsigned short* dst = sAb + (q) * 20480;                                   \
    _Pragma("unroll")                                                          \
    for (int i = 0; i < 5; ++i) {                                              \
      int o = i * 8192 + tid * 16;                                             \
      int kh2 = o / 20480, o2 = o - kh2 * 20480;                               \
      int r = o2 / 640, b = o2 - r * 640;                                      \
      *(bf16x8*)&dst[kh2 * 10240 + r * 320 + ((b ^ ((r & 7) << 4)) >> 1)] = st[i]; \
    } }

  f32x4 acc[2][5] = {};
  const unsigned short* Bcol = wvf + (size_t)(cs * 80 + lm) * 2560 + kh * 1280 + qd * 8;

  STAGE_LOAD(0); STAGE_WRITE(0);
  __syncthreads();

  for (int p = 0; p < 4; ++p) {
    if (p < 3) STAGE_LOAD(p + 1);                 // issue early — hides under compute
    const unsigned short* Ab = sAb + (p & 1) * 20480 + kh * 10240;
    const unsigned short* Bp = Bcol + p * 320;
    bf16x8 breg[3][5];
    #pragma unroll
    for (int s = 0; s < 2; ++s)
      #pragma unroll
      for (int u = 0; u < 5; ++u)
        breg[s][u] = *(const bf16x8*)(Bp + (size_t)u * 16 * 2560 + s * 32);
    #pragma unroll
    for (int kt = 0; kt < 10; ++kt) {
      const int cur = kt % 3, nxt = (kt + 2) % 3;
      if (kt + 2 < 10) {
        #pragma unroll
        for (int u = 0; u < 5; ++u)
          breg[nxt][u] = *(const bf16x8*)(Bp + (size_t)u * 16 * 2560 + (kt + 2) * 32);
      }
      const int b0 = kt * 64 + qd * 16;
      const int r0 = lm, r1 = 16 + lm;
      bf16x8 a0 = *(const bf16x8*)&Ab[r0 * 320 + ((b0 ^ ((r0 & 7) << 4)) >> 1)];
      bf16x8 a1 = *(const bf16x8*)&Ab[r1 * 320 + ((b0 ^ ((r1 & 7) << 4)) >> 1)];
      #pragma unroll
      for (int u = 0; u < 5; ++u) {
        acc[0][u] = MFMA16(a0, breg[cur][u], acc[0][u]);
        acc[1][u] = MFMA16(a1, breg[cur][u], acc[1][u]);
      }
    }
    if (p < 3) {
      STAGE_WRITE((p + 1) & 1);
      __syncthreads();
    }
  }

  // ---- kh merge through LDS f32 (overlay on sAb; all compute done) --------
  __syncthreads();
  float* sX = (float*)sAb;                        // 32 x 324 f32 = 41.5 KB
  if (kh == 0) {
    #pragma unroll
    for (int mt = 0; mt < 2; ++mt)
      #pragma unroll
      for (int u = 0; u < 5; ++u)
        #pragma unroll
        for (int r = 0; r < 4; ++r)
          sX[(mt * 16 + qd * 4 + r) * 324 + cs * 80 + u * 16 + lm] = acc[mt][u][r];
  }
  __syncthreads();
  if (kh == 1) {
    #pragma unroll
    for (int mt = 0; mt < 2; ++mt)
      #pragma unroll
      for (int u = 0; u < 5; ++u)
        #pragma unroll
        for (int r = 0; r < 4; ++r)
          sX[(mt * 16 + qd * 4 + r) * 324 + cs * 80 + u * 16 + lm] += acc[mt][u][r];
  }
  // stage h_dst bf16 (independent of sX — do before the barrier)
  {
    int nn = tid >> 4, kk = (tid & 15) * 8;
    const float4* src = (const float4*)(nf + (size_t)(n0 + nn) * NODE_IN + kk);
    float4 f0 = src[0], f1 = src[1];
    float v8[8] = {f0.x, f0.y, f0.z, f0.w, f1.x, f1.y, f1.z, f1.w};
    *(bf16x8*)&sQb[nn * 136 + kk] = pack8(v8);
  }
  __syncthreads();

  // ---- LN: thread owns (row rr, cols cl+16u); reduce over 16-lane group ---
  const int rr = tid >> 4, cl = tid & 15;
  float v[20], s1 = 0.f, s2 = 0.f;
  #pragma unroll
  for (int u = 0; u < 20; ++u) {
    int c = u * 16 + cl;
    float x = sX[rr * 324 + c] + f32r[F_CC + c];
    if (c < 128) x += nf[(size_t)(n0 + rr) * NODE_IN + c];
    v[u] = x; s1 += x; s2 += x * x;
  }
  #pragma unroll
  for (int off = 8; off >= 1; off >>= 1) { s1 += __shfl_xor(s1, off); s2 += __shfl_xor(s2, off); }
  float mean = s1 * (1.f / D_MODEL);
  float var  = s2 * (1.f / D_MODEL) - mean * mean;
  float rstd = rsqrtf(var + 1e-5f);
  #pragma unroll
  for (int u = 0; u < 20; ++u) {
    int c = u * 16 + cl;
    sXb[rr * 328 + c] = f2bf((v[u] - mean) * rstd);
  }
  __syncthreads();

  // ---- out GEMM: M=32, N=128, K=448; 8 waves x 2 tasks (rh, ot) -----------
  #pragma unroll
  for (int t = 0; t < 2; ++t) {
    int task = wid * 2 + t;
    int rh = task >> 3, ot = task & 7;
    int o = ot * 16 + lm;
    f32x4 oacc = {};
    for (int kt = 0; kt < 14; ++kt) {
      bf16x8 a;
      if (kt < 4) a = *(const bf16x8*)&sQb[(rh * 16 + lm) * 136 + kt * 32 + qd * 8];
      else        a = *(const bf16x8*)&sXb[(rh * 16 + lm) * 328 + (kt - 4) * 32 + qd * 8];
      bf16x8 b = *(const bf16x8*)&nwc[(size_t)o * IN2 + kt * 32 + qd * 8];
      oacc = MFMA16(a, b, oacc);
    }
    float bz = f32r[F_B2 + o];
    #pragma unroll
    for (int r = 0; r < 4; ++r)
      out[(size_t)(n0 + rh * 16 + qd * 4 + r) * HID + o] = fmaxf(oacc[r] + bz, 0.f);
  }
  #undef STAGE_LOAD
  #undef STAGE_WRITE
}

extern "C" void kernel_launch(void* const* d_in, const int* in_sizes, int n_in,
                              void* d_out, int out_size, void* d_ws, size_t ws_size,
                              hipStream_t stream) {
  const float* nf   = (const float*)d_in[0];
  const float* ef   = (const float*)d_in[1];
  const float* dtp  = (const float*)d_in[2];
  const int*   nidx = (const int*)  d_in[3];
  const float* freq = (const float*)d_in[4];
  const float* ph   = (const float*)d_in[5];
  const float* wq   = (const float*)d_in[6];
  const float* wk   = (const float*)d_in[7];
  const float* wv   = (const float*)d_in[8];
  const float* fcw  = (const float*)d_in[9];
  const float* fcb  = (const float*)d_in[10];
  const float* lng  = (const float*)d_in[11];
  const float* lnb_ = (const float*)d_in[12];
  const float* nw   = (const float*)d_in[13];
  const float* nb   = (const float*)d_in[14];
  float* out = (float*)d_out;
  unsigned short* ws = (unsigned short*)d_ws;
  unsigned short* qkm = ws + WS_QKM;

  prep1a  <<<226, 256, 0, stream>>>(nw, lng, fcb, ph, ws);
  prep1b  <<<160, 256, 0, stream>>>(wq, ph, nw, lnb_, nb, ws);
  prep_c0k<<<640, 256, 0, stream>>>(wk, ws);
  prep_wqk<<<80,  256, 0, stream>>>(wq, wk, ws);
  prep_wvf<<<800, 256, 0, stream>>>(fcw, wv, ws);
  tgat_qk   <<<2560, 256, 0, stream>>>(nf, ws, qkm);
  tgat_attn <<<8192, 256, 0, stream>>>(nf, ef, dtp, nidx, freq, ph, qkm);
  tgat_xgemm<<<256,  512, 0, stream>>>(nf, ws, qkm, out);
}

// Round 5
// 253.828 us; speedup vs baseline: 1.2813x; 1.0648x over previous
//
#include <hip/hip_runtime.h>
#include <math.h>

#define LNB      32
#define NODE_IN  128
#define EDGE_IN  64
#define TIME_D   128
#define D_MODEL  320
#define N_HEAD   8
#define D_K      64
#define NHD      512
#define HID      128
#define IN2      448
#define N_DSTN   8192

typedef __attribute__((ext_vector_type(8))) short bf16x8;
typedef __attribute__((ext_vector_type(4))) float f32x4;
#define MFMA16(a,b,c) __builtin_amdgcn_mfma_f32_16x16x32_bf16(a,b,c,0,0,0)

// ---- ws layout (elements of unsigned short) ----
#define WS_QKM   0            // 8192*2560 : qk (h-major) -> mbar (d*8+h layout), in place
#define WS_WQK   20971520     // 2560*128  : folded wk@wq   (row-major [h*320+d][k])
#define WS_WVF   21299200     // 320*2560  : folded fcw@wv  ([c][d*8+h])
#define WS_NWC   22118400     // 128*448   : [nw1 | nw2*lng]
#define WS_F32   22175744     // 3520 floats
#define WS_X     22182784     // 8192*320 f32 x buffer (plain stores, full-K blocks)
// total = 27,425,664 shorts = 54.9 MB

#define F_C0     0            // 512
#define F_C0K    512          // 2560
#define F_CC     3072         // 320 : fcb + q-const residual
#define F_B2     3392         // 128 : nb + nw2@lnb

// native RTNE f32->bf16 (v_cvt_pk_bf16_f32 on gfx950) — bit-identical to manual RTNE
__device__ __forceinline__ unsigned short f2bf(float f) {
  __bf16 h = (__bf16)f;
  return __builtin_bit_cast(unsigned short, h);
}
__device__ __forceinline__ bf16x8 pack8(const float* v) {
  unsigned short b8[8];
  #pragma unroll
  for (int j = 0; j < 8; ++j) b8[j] = f2bf(v[j]);
  return *(const bf16x8*)b8;
}

// async global->LDS, 16 B per lane; LDS dest = wave-uniform base + lane*16
#define GLDS(srcp, dstp) __builtin_amdgcn_global_load_lds(                     \
    (const __attribute__((address_space(1))) unsigned int*)(const void*)(srcp),\
    (__attribute__((address_space(3))) unsigned int*)(void*)(dstp), 16, 0, 0)

// =================== prep1a: elementwise folds ==============================
__global__ __launch_bounds__(256)
void prep1a(const float* __restrict__ nw, const float* __restrict__ lng,
            const float* __restrict__ fcb, const float* __restrict__ ph,
            unsigned short* __restrict__ ws)
{
  int i = blockIdx.x * 256 + threadIdx.x;
  unsigned short* nwc = ws + WS_NWC;
  float* f32r = (float*)(ws + WS_F32);
  if (i < 16384) {                       // nw1 cast
    int o = i >> 7, k = i & 127;
    nwc[o * IN2 + k] = f2bf(nw[(size_t)o * IN2 + k]);
  } else if (i < 57344) {                // nw2g = nw2 * lng
    int j = i - 16384, o = j / 320, c = j - o * 320;
    nwc[o * IN2 + 128 + c] = f2bf(nw[(size_t)o * IN2 + 128 + c] * lng[c]);
  } else if (i < 57664) {                // cc[c] = fcb + q-const
    int c = i - 57344;
    f32r[F_CC + c] = fcb[c] + (c >= 192 ? __cosf(ph[c - 192]) : 0.f);
  }
}

// =================== prep1b: c0 (512 waves) + b2 (128 waves) ===============
__global__ __launch_bounds__(256)
void prep1b(const float* __restrict__ wq, const float* __restrict__ ph,
            const float* __restrict__ nw, const float* __restrict__ lnb_,
            const float* __restrict__ nb, unsigned short* __restrict__ ws)
{
  float* f32r = (float*)(ws + WS_F32);
  int gw = (blockIdx.x * 256 + threadIdx.x) >> 6;
  int ln = threadIdx.x & 63;
  if (gw < 512) {                        // c0[j] = cos(ph) . wq[j][192:]
    float s = __cosf(ph[ln])      * wq[(size_t)gw * D_MODEL + 192 + ln]
            + __cosf(ph[ln + 64]) * wq[(size_t)gw * D_MODEL + 256 + ln];
    #pragma unroll
    for (int off = 32; off >= 1; off >>= 1) s += __shfl_xor(s, off);
    if (ln == 0) f32r[F_C0 + gw] = s;
  } else {                               // b2[o] = nb + nw2 . lnb
    int o = gw - 512;
    float s = 0.f;
    #pragma unroll
    for (int k = 0; k < 5; ++k) {
      int c = ln + 64 * k;
      s += nw[(size_t)o * IN2 + 128 + c] * lnb_[c];
    }
    #pragma unroll
    for (int off = 32; off >= 1; off >>= 1) s += __shfl_xor(s, off);
    if (ln == 0) f32r[F_B2 + o] = nb[o] + s;
  }
}

// =================== prep_c0k: one wave per hd ==============================
__global__ __launch_bounds__(256)
void prep_c0k(const float* __restrict__ wk, unsigned short* __restrict__ ws)
{
  float* f32r = (float*)(ws + WS_F32);
  int gw = (blockIdx.x * 256 + threadIdx.x) >> 6;   // 0..2559
  int ln = threadIdx.x & 63;
  int h = gw / 320, d = gw - h * 320;
  float s = f32r[F_C0 + h * 64 + ln] * wk[(size_t)(h * 64 + ln) * D_MODEL + d];
  #pragma unroll
  for (int off = 32; off >= 1; off >>= 1) s += __shfl_xor(s, off);
  if (ln == 0) f32r[F_C0K + gw] = s;
}

// =================== prep_wqk: LDS-tiled fold (80 blocks) ===================
__global__ __launch_bounds__(256)
void prep_wqk(const float* __restrict__ wq, const float* __restrict__ wk,
              unsigned short* __restrict__ ws)
{
  __shared__ float sQw[64 * 128];
  __shared__ float sKw[64 * 32];
  int h = blockIdx.x / 10, d0 = (blockIdx.x - h * 10) * 32;
  int tid = threadIdx.x;
  #pragma unroll 4
  for (int it = 0; it < 32; ++it) {
    int idx = it * 256 + tid;
    int r = idx >> 7, c = idx & 127;
    sQw[idx] = wq[(size_t)(h * 64 + r) * D_MODEL + c];
  }
  #pragma unroll
  for (int it = 0; it < 8; ++it) {
    int idx = it * 256 + tid;
    int r = idx >> 5, c = idx & 31;
    sKw[idx] = wk[(size_t)(h * 64 + r) * D_MODEL + d0 + c];
  }
  __syncthreads();
  int di = tid >> 3, k0 = (tid & 7) * 16;
  float acc[16] = {};
  for (int dk = 0; dk < 64; ++dk) {
    float w = sKw[dk * 32 + di];
    #pragma unroll
    for (int j = 0; j < 16; ++j) acc[j] += w * sQw[dk * 128 + k0 + j];
  }
  unsigned short* dst = ws + WS_WQK + (size_t)(h * 320 + d0 + di) * 128 + k0;
  #pragma unroll
  for (int j = 0; j < 16; ++j) dst[j] = f2bf(acc[j]);
}

// =================== prep_wvf: LDS-tiled fold (800 blocks) ==================
// wvf[c][d*8+h] = sum_jj fcw[c][h*64+jj] * wv[h*64+jj][d]
__global__ __launch_bounds__(256)
void prep_wvf(const float* __restrict__ fcw, const float* __restrict__ wv,
              unsigned short* __restrict__ ws)
{
  __shared__ float sF[32 * 64];
  __shared__ float sW[64 * 32];
  int b = blockIdx.x;
  int h = b / 100, r2 = b - h * 100;
  int ct = r2 / 10;
  int c0 = ct * 32, d0 = (r2 - ct * 10) * 32;
  int tid = threadIdx.x;
  #pragma unroll
  for (int it = 0; it < 8; ++it) {
    int idx = it * 256 + tid;
    int i = idx >> 6, jj = idx & 63;
    sF[idx] = fcw[(size_t)(c0 + i) * NHD + h * 64 + jj];
  }
  #pragma unroll
  for (int it = 0; it < 8; ++it) {
    int idx = it * 256 + tid;
    int jj = idx >> 5, i = idx & 31;
    sW[idx] = wv[(size_t)(h * 64 + jj) * D_MODEL + d0 + i];
  }
  __syncthreads();
  int ci = tid >> 3, dj0 = (tid & 7) * 4;
  float acc[4] = {};
  for (int jj = 0; jj < 64; ++jj) {
    float f = sF[ci * 64 + jj];
    #pragma unroll
    for (int k = 0; k < 4; ++k) acc[k] += f * sW[jj * 32 + dj0 + k];
  }
  unsigned short* wvf = ws + WS_WVF;
  #pragma unroll
  for (int k = 0; k < 4; ++k)
    wvf[(size_t)(c0 + ci) * 2560 + (size_t)(d0 + dj0 + k) * 8 + h] = f2bf(acc[k]);
}

// =================== K1: qk = nf @ wqk^T + c0k  (h-major layout) ============
__global__ __launch_bounds__(256, 6)
void tgat_qk(const float* __restrict__ nf, const unsigned short* __restrict__ ws,
             unsigned short* __restrict__ qkm)
{
  __shared__ alignas(16) unsigned short sA[64 * 136];
  const int tid = threadIdx.x, wid = tid >> 6, lane = tid & 63, qd = lane >> 4, lm = lane & 15;
  const int mt_blk = blockIdx.x / 20, nt_blk = blockIdx.x - mt_blk * 20;
  const int n0 = mt_blk * 64, c0 = nt_blk * 128;
  const unsigned short* wqk = ws + WS_WQK;
  const float* f32r = (const float*)(ws + WS_F32);

  { // stage A: 64 x 128 bf16 (coalesced)
    int n = tid >> 2, k0 = (tid & 3) * 32;
    const float4* src = (const float4*)(nf + (size_t)(n0 + n) * NODE_IN + k0);
    #pragma unroll
    for (int q = 0; q < 4; ++q) {
      float4 f0 = src[2 * q], f1 = src[2 * q + 1];
      float v[8] = {f0.x, f0.y, f0.z, f0.w, f1.x, f1.y, f1.z, f1.w};
      *(bf16x8*)&sA[n * 136 + k0 + q * 8] = pack8(v);
    }
  }
  __syncthreads();

  f32x4 acc[2][4] = {};
  for (int kt = 0; kt < 4; ++kt) {
    bf16x8 a[4];
    #pragma unroll
    for (int mt = 0; mt < 4; ++mt)
      a[mt] = *(const bf16x8*)&sA[(mt * 16 + lm) * 136 + kt * 32 + qd * 8];
    #pragma unroll
    for (int t = 0; t < 2; ++t) {
      int cg = c0 + (2 * wid + t) * 16 + lm;
      bf16x8 b = *(const bf16x8*)&wqk[(size_t)cg * 128 + kt * 32 + qd * 8];
      #pragma unroll
      for (int mt = 0; mt < 4; ++mt) acc[t][mt] = MFMA16(a[mt], b, acc[t][mt]);
    }
  }
  #pragma unroll
  for (int t = 0; t < 2; ++t) {
    int cg = c0 + (2 * wid + t) * 16 + lm;
    float ck = f32r[F_C0K + cg];
    #pragma unroll
    for (int mt = 0; mt < 4; ++mt)
      #pragma unroll
      for (int r = 0; r < 4; ++r)
        qkm[(size_t)(n0 + mt * 16 + qd * 4 + r) * 2560 + cg] = f2bf(acc[t][mt][r] + ck);
  }
}

// =================== K2: attention (one barrier before scores) ==============
__global__ __launch_bounds__(256, 6)
void tgat_attn(const float* __restrict__ nf, const float* __restrict__ ef,
               const float* __restrict__ dtp, const int* __restrict__ nidx,
               const float* __restrict__ freq, const float* __restrict__ ph,
               unsigned short* __restrict__ qkm)
{
  __shared__ alignas(16) unsigned short sM[LNB * 328];    // 21 KB
  __shared__ alignas(16) unsigned short sATT[16 * 40];    // 1.25 KB

  const int tid = threadIdx.x;
  const int wid = tid >> 6, lane = tid & 63, qd = lane >> 4, lm = lane & 15;
  const int n = blockIdx.x;
  unsigned short* qn = qkm + (size_t)n * 2560;

  // ---- m build: thread -> (l = g&31, 8 consecutive d); tables direct from L2
  #pragma unroll 1
  for (int it = 0; it < 5; ++it) {
    int g = it * 256 + tid;
    int l = g & 31, dg = g >> 5;
    int d0 = dg * 8;
    float v[8];
    if (dg < 16) {
      int ni = nidx[n * 16 + (l >> 1)];
      const float4* src = (const float4*)(nf + (size_t)ni * NODE_IN + d0);
      float4 f0 = src[0], f1 = src[1];
      v[0]=f0.x; v[1]=f0.y; v[2]=f0.z; v[3]=f0.w; v[4]=f1.x; v[5]=f1.y; v[6]=f1.z; v[7]=f1.w;
    } else if (dg < 24) {
      const float4* src = (const float4*)(ef + ((size_t)n * LNB + l) * EDGE_IN + (d0 - NODE_IN));
      float4 f0 = src[0], f1 = src[1];
      v[0]=f0.x; v[1]=f0.y; v[2]=f0.z; v[3]=f0.w; v[4]=f1.x; v[5]=f1.y; v[6]=f1.z; v[7]=f1.w;
    } else {
      int dd = d0 - 192;
      float dt = dtp[(size_t)n * LNB + l];
      const float4* fq = (const float4*)(freq + dd);
      const float4* pp = (const float4*)(ph + dd);
      float4 q0 = fq[0], q1 = fq[1], p0 = pp[0], p1 = pp[1];
      v[0] = __cosf(dt * q0.x + p0.x); v[1] = __cosf(dt * q0.y + p0.y);
      v[2] = __cosf(dt * q0.z + p0.z); v[3] = __cosf(dt * q0.w + p0.w);
      v[4] = __cosf(dt * q1.x + p1.x); v[5] = __cosf(dt * q1.y + p1.y);
      v[6] = __cosf(dt * q1.z + p1.z); v[7] = __cosf(dt * q1.w + p1.w);
    }
    *(bf16x8*)&sM[l * 328 + d0] = pack8(v);
  }

  // wave0: issue qk B-frag loads now — latency hides under the barrier wait
  bf16x8 qfrag[10];
  if (wid == 0) {
    #pragma unroll
    for (int kt = 0; kt < 10; ++kt) {
      qfrag[kt] = (bf16x8){0,0,0,0,0,0,0,0};
      if (lm < 8) qfrag[kt] = *(const bf16x8*)&qn[lm * 320 + kt * 32 + qd * 8];
    }
  }
  __syncthreads();                       // barrier 1: m ready

  // mbar tile ownership: wave0 -> 2 tiles, waves1-3 -> 6 each (20 total)
  const int tbeg = (wid == 0) ? 0 : 2 + (wid - 1) * 6;
  const int tcnt = (wid == 0) ? 2 : 6;
  bf16x8 afr[6];

  if (wid == 0) {
    // scores: D[l][h] = m @ qk^T / 8
    f32x4 acc0 = {}, acc1 = {};
    #pragma unroll
    for (int kt = 0; kt < 10; ++kt) {
      bf16x8 a0 = *(const bf16x8*)&sM[lm * 328 + kt * 32 + qd * 8];
      bf16x8 a1 = *(const bf16x8*)&sM[(16 + lm) * 328 + kt * 32 + qd * 8];
      acc0 = MFMA16(a0, qfrag[kt], acc0);
      acc1 = MFMA16(a1, qfrag[kt], acc1);
    }
    float s[8], e[8];
    #pragma unroll
    for (int r = 0; r < 4; ++r) { s[r] = acc0[r] * 0.125f; s[4 + r] = acc1[r] * 0.125f; }
    float mx = s[0];
    #pragma unroll
    for (int i = 1; i < 8; ++i) mx = fmaxf(mx, s[i]);
    mx = fmaxf(mx, __shfl_xor(mx, 16));
    mx = fmaxf(mx, __shfl_xor(mx, 32));
    float sum = 0.f;
    #pragma unroll
    for (int i = 0; i < 8; ++i) { e[i] = __expf(s[i] - mx); sum += e[i]; }
    sum += __shfl_xor(sum, 16);
    sum += __shfl_xor(sum, 32);
    float inv = 1.f / sum;
    #pragma unroll
    for (int i = 0; i < 8; ++i) {
      int l = (i < 4) ? (qd * 4 + i) : (16 + qd * 4 + (i - 4));
      sATT[lm * 40 + l] = f2bf(e[i] * inv);
    }
  } else {
    // waves 1-3: prefetch transposed-m A-frags for my 6 tiles (overlaps softmax)
    #pragma unroll
    for (int u = 0; u < 6; ++u) {
      int d = (tbeg + u) * 16 + lm;
      unsigned short a8[8];
      #pragma unroll
      for (int j = 0; j < 8; ++j) a8[j] = sM[(qd * 8 + j) * 328 + d];
      afr[u] = *(const bf16x8*)a8;
    }
  }
  __syncthreads();                       // barrier 2: sATT ready

  if (wid == 0) {                        // wave0 fetches its 2 tiles now
    #pragma unroll
    for (int u = 0; u < 2; ++u) {
      int d = u * 16 + lm;
      unsigned short a8[8];
      #pragma unroll
      for (int j = 0; j < 8; ++j) a8[j] = sM[(qd * 8 + j) * 328 + d];
      afr[u] = *(const bf16x8*)a8;
    }
  }
  bf16x8 batt = *(const bf16x8*)&sATT[lm * 40 + qd * 8];
  #pragma unroll
  for (int u = 0; u < 6; ++u) {
    if (u < tcnt) {                      // wave-uniform guard
      int dtile = tbeg + u;
      f32x4 acc = {};
      acc = MFMA16(afr[u], batt, acc);
      if (lm < 8) {
        #pragma unroll
        for (int r = 0; r < 4; ++r)
          qn[(dtile * 16 + qd * 4 + r) * 8 + lm] = f2bf(acc[r]);
      }
    }
  }
}

// =================== K3a: x = mbar @ wvf^T (m97-structure, gload_lds) =======
// 256 blocks (64 mb x 4 nb) x 512 thr. Block = 128 rows x 80 cols, full K.
// bid mapping: xcd = bid&7 = mb&7 -> the 4 nb-blocks of one mb share an XCD
// (A re-reads hit that XCD's L2). 8 waves = 8 m-strips of 16 rows; wave tile
// 16x80 (5 n-tiles). K: 20 chunks of 128, double-buffered LDS (104 KB),
// staged with global_load_lds width=16 (no staging registers -> compiler
// can't sink the pipeline). LDS compute reads are lgkmcnt — independent of
// the vmcnt staging stream. Source-block XOR swizzle (b ^= r&7 on 16B-block
// index) makes ds_read_b128 2-way max (free). One barrier per chunk.
__global__ __launch_bounds__(512, 1)
void tgat_xgemm(const unsigned short* __restrict__ ws,
                const unsigned short* __restrict__ qkm, float* __restrict__ xacc)
{
  __shared__ alignas(16) unsigned short sA[2][128 * 128];  // 64 KB
  __shared__ alignas(16) unsigned short sB[2][80 * 128];   // 40 KB
  const int tid = threadIdx.x, wid = tid >> 6, lane = tid & 63;
  const int qd = lane >> 4, lm = lane & 15;
  const int xcd = blockIdx.x & 7, j = blockIdx.x >> 3;
  const int nb = j & 3, mb = xcd + 8 * (j >> 2);
  const int n0 = mb * 128, c0 = nb * 80;
  const unsigned short* wvf = ws + WS_WVF;

  const int rhi = lane >> 4, blo = lane & 15;

  // stage chunk kc into buffer buf: 52 wave-rounds of 1 KB (A 32 + B 20),
  // wave w does rounds w, w+8, ... ; source 16B-block index pre-swizzled.
  #define STAGE(kc, buf) {                                                     \
    for (int ri = wid; ri < 52; ri += 8) {                                     \
      if (ri < 32) {                                                           \
        int r = ri * 4 + rhi;                                                  \
        int blk = blo ^ (r & 7);                                               \
        GLDS(qkm + (size_t)(n0 + r) * 2560 + (kc) * 128 + blk * 8,             \
             &sA[buf][ri * 512]);                                              \
      } else {                                                                 \
        int jb = ri - 32;                                                      \
        int r = jb * 4 + rhi;                                                  \
        int blk = blo ^ (r & 7);                                               \
        GLDS(wvf + (size_t)(c0 + r) * 2560 + (kc) * 128 + blk * 8,             \
             &sB[buf][jb * 512]);                                              \
      }                                                                        \
    } }

  f32x4 acc[5] = {};
  STAGE(0, 0);
  __syncthreads();

  for (int c = 0; c < 20; ++c) {
    if (c < 19) STAGE(c + 1, (c + 1) & 1);      // issue-early into other buffer
    const unsigned short* Ab = sA[c & 1];
    const unsigned short* Bb = sB[c & 1];
    const int s = lm & 7;
    #pragma unroll
    for (int kt = 0; kt < 4; ++kt) {
      const int blk = ((kt << 2) | qd) ^ s;
      bf16x8 a = *(const bf16x8*)&Ab[(wid * 16 + lm) * 128 + blk * 8];
      #pragma unroll
      for (int u = 0; u < 5; ++u) {
        bf16x8 b = *(const bf16x8*)&Bb[(u * 16 + lm) * 128 + blk * 8];
        acc[u] = MFMA16(a, b, acc[u]);
      }
    }
    __syncthreads();                             // drains staging, frees buffer
  }

  #pragma unroll
  for (int u = 0; u < 5; ++u)
    #pragma unroll
    for (int r = 0; r < 4; ++r)
      xacc[(size_t)(n0 + wid * 16 + qd * 4 + r) * 320 + c0 + u * 16 + lm] = acc[u][r];
  #undef STAGE
}

// =================== K3b: LN + out GEMM (512 blocks) ========================
__global__ __launch_bounds__(256, 4)
void tgat_post2(const float* __restrict__ nf, const unsigned short* __restrict__ ws,
                const float* __restrict__ xacc, float* __restrict__ out)
{
  __shared__ alignas(16) unsigned short sQb[16 * 136];
  __shared__ alignas(16) unsigned short sXb[16 * 328];
  const int tid = threadIdx.x, wid = tid >> 6, lane = tid & 63, qd = lane >> 4, lm = lane & 15;
  const int n0 = blockIdx.x * 16;
  const unsigned short* nwc = ws + WS_NWC;
  const float* f32r = (const float*)(ws + WS_F32);

  { // stage h_dst bf16
    int nn = tid >> 4, kk = (tid & 15) * 8;
    const float4* src = (const float4*)(nf + (size_t)(n0 + nn) * NODE_IN + kk);
    float4 f0 = src[0], f1 = src[1];
    float v8[8] = {f0.x, f0.y, f0.z, f0.w, f1.x, f1.y, f1.z, f1.w};
    *(bf16x8*)&sQb[nn * 136 + kk] = pack8(v8);
  }
  // LN: thread owns (row rr, cols cl+16u); reduce over the 16-lane row group
  const int rr = tid >> 4, cl = tid & 15;
  float v[20], s1 = 0.f, s2 = 0.f;
  #pragma unroll
  for (int u = 0; u < 20; ++u) {
    int c = u * 16 + cl;
    float x = xacc[(size_t)(n0 + rr) * 320 + c] + f32r[F_CC + c];
    if (c < 128) x += nf[(size_t)(n0 + rr) * NODE_IN + c];
    v[u] = x; s1 += x; s2 += x * x;
  }
  #pragma unroll
  for (int off = 8; off >= 1; off >>= 1) { s1 += __shfl_xor(s1, off); s2 += __shfl_xor(s2, off); }
  float mean = s1 * (1.f / D_MODEL);
  float var  = s2 * (1.f / D_MODEL) - mean * mean;
  float rstd = rsqrtf(var + 1e-5f);
  #pragma unroll
  for (int u = 0; u < 20; ++u) {
    int c = u * 16 + cl;
    sXb[rr * 328 + c] = f2bf((v[u] - mean) * rstd);
  }
  __syncthreads();

  // out GEMM: M=16, N=128, K=448; 4 waves x 2 o-tiles
  #pragma unroll
  for (int t = 0; t < 2; ++t) {
    int o = (wid * 2 + t) * 16 + lm;
    f32x4 acc = {};
    for (int kt = 0; kt < 14; ++kt) {
      bf16x8 a;
      if (kt < 4) a = *(const bf16x8*)&sQb[lm * 136 + kt * 32 + qd * 8];
      else        a = *(const bf16x8*)&sXb[lm * 328 + (kt - 4) * 32 + qd * 8];
      bf16x8 b = *(const bf16x8*)&nwc[(size_t)o * IN2 + kt * 32 + qd * 8];
      acc = MFMA16(a, b, acc);
    }
    float bz = f32r[F_B2 + o];
    #pragma unroll
    for (int r = 0; r < 4; ++r)
      out[(size_t)(n0 + qd * 4 + r) * HID + o] = fmaxf(acc[r] + bz, 0.f);
  }
}

extern "C" void kernel_launch(void* const* d_in, const int* in_sizes, int n_in,
                              void* d_out, int out_size, void* d_ws, size_t ws_size,
                              hipStream_t stream) {
  const float* nf   = (const float*)d_in[0];
  const float* ef   = (const float*)d_in[1];
  const float* dtp  = (const float*)d_in[2];
  const int*   nidx = (const int*)  d_in[3];
  const float* freq = (const float*)d_in[4];
  const float* ph   = (const float*)d_in[5];
  const float* wq   = (const float*)d_in[6];
  const float* wk   = (const float*)d_in[7];
  const float* wv   = (const float*)d_in[8];
  const float* fcw  = (const float*)d_in[9];
  const float* fcb  = (const float*)d_in[10];
  const float* lng  = (const float*)d_in[11];
  const float* lnb_ = (const float*)d_in[12];
  const float* nw   = (const float*)d_in[13];
  const float* nb   = (const float*)d_in[14];
  float* out = (float*)d_out;
  unsigned short* ws = (unsigned short*)d_ws;
  unsigned short* qkm = ws + WS_QKM;
  float* xacc = (float*)(ws + WS_X);

  prep1a  <<<226, 256, 0, stream>>>(nw, lng, fcb, ph, ws);
  prep1b  <<<160, 256, 0, stream>>>(wq, ph, nw, lnb_, nb, ws);
  prep_c0k<<<640, 256, 0, stream>>>(wk, ws);
  prep_wqk<<<80,  256, 0, stream>>>(wq, wk, ws);
  prep_wvf<<<800, 256, 0, stream>>>(fcw, wv, ws);
  tgat_qk   <<<2560, 256, 0, stream>>>(nf, ws, qkm);
  tgat_attn <<<8192, 256, 0, stream>>>(nf, ef, dtp, nidx, freq, ph, qkm);
  tgat_xgemm<<<256,  512, 0, stream>>>(ws, qkm, xacc);
  tgat_post2<<<512,  256, 0, stream>>>(nf, ws, xacc, out);
}